// Round 11
// baseline (469.904 us; speedup 1.0000x reference)
//
#include <hip/hip_runtime.h>
#include <cmath>

#define NB 8
#define NN 16384
#define DIN 23
#define DOUT 16

typedef short bf16x8 __attribute__((ext_vector_type(8)));
typedef float f32x4 __attribute__((ext_vector_type(4)));

__device__ __forceinline__ unsigned short f2bf(float f) {
    unsigned int u = __float_as_uint(f);
    u += 0x7FFFu + ((u >> 16) & 1u);
    return (unsigned short)(u >> 16);
}
__device__ __forceinline__ float bf2f(unsigned short s) {
    return __uint_as_float(((unsigned int)s) << 16);
}
__device__ __forceinline__ float rcpf(float x) { return __builtin_amdgcn_rcpf(x); }

__device__ __forceinline__ bf16x8 cvt8(float4 a, float4 b) {
    bf16x8 r;
    r[0]=(short)f2bf(a.x); r[1]=(short)f2bf(a.y); r[2]=(short)f2bf(a.z); r[3]=(short)f2bf(a.w);
    r[4]=(short)f2bf(b.x); r[5]=(short)f2bf(b.y); r[6]=(short)f2bf(b.z); r[7]=(short)f2bf(b.w);
    return r;
}
__device__ __forceinline__ void red16(f32x4& s) {
    #pragma unroll
    for (int off = 1; off < 16; off <<= 1) {
        s[0] += __shfl_xor(s[0], off); s[1] += __shfl_xor(s[1], off);
        s[2] += __shfl_xor(s[2], off); s[3] += __shfl_xor(s[3], off);
    }
}
__device__ __forceinline__ void red16x2(f32x4& s, f32x4& w) {
    #pragma unroll
    for (int off = 1; off < 16; off <<= 1) {
        s[0] += __shfl_xor(s[0], off); s[1] += __shfl_xor(s[1], off);
        s[2] += __shfl_xor(s[2], off); s[3] += __shfl_xor(s[3], off);
        w[0] += __shfl_xor(w[0], off); w[1] += __shfl_xor(w[1], off);
        w[2] += __shfl_xor(w[2], off); w[3] += __shfl_xor(w[3], off);
    }
}

// workspace offsets in floats
#define WS_XSPB   ((size_t)0)
#define WS_GPART  ((size_t)8388608)
#define WS_VB     ((size_t)16777216)
#define WS_XSB    ((size_t)25165824)
#define WS_FS     ((size_t)33554432)
#define WS_INV    ((size_t)35651584)
#define WS_CS     ((size_t)35651648)
#define WS_CC     ((size_t)35653184)
#define WS_WCAT   ((size_t)35654720)
#define WS_BCAT   ((size_t)35703872)
#define WS_KVPART ((size_t)35704256)
#define WS_KMPART ((size_t)37801408)
#define WS_KV     ((size_t)37866944)
#define WS_KMEAN  ((size_t)37932480)
#define WS_QN2    ((size_t)37934528)
#define WS_KN2    ((size_t)37935552)
#define WS_ATTN   ((size_t)38067648)
#define WS_BMATT  ((size_t)38198720)
#define WS_QB     ((size_t)38460864)
#define WS_KB     ((size_t)46849472)

// ---------------------------------------------------------------- weights prep + setup (merged)
__global__ __launch_bounds__(256) void k_wprep(
    const float* __restrict__ Wq, const float* __restrict__ Wk, const float* __restrict__ Wv,
    const float* __restrict__ bq, const float* __restrict__ bk, const float* __restrict__ bv,
    const float* __restrict__ sc, const float* __restrict__ ccin,
    unsigned short* __restrict__ Wc, float* __restrict__ bcat,
    float* __restrict__ inv, float* __restrict__ cs, float* __restrict__ cc)
{
    int row = blockIdx.x, t = threadIdx.x;
    if (row == 384) {
        if (t >= 64) return;
        if (t < DIN) inv[t] = (float)pow(10000.0, -((double)(2 * t)) / 64.0);
        int h = t >> 4, d = t & 15;
        float ss = 0.f, s2 = 0.f;
        for (int D = 0; D < DIN; ++D) { ss += sc[(h*DIN + D)*DOUT + d]; s2 += ccin[(h*DIN + D)*DOUT + d]; }
        float rs = 1.f / ss, r2 = 1.f / s2;
        for (int D = 0; D < DIN; ++D) {
            cs[(h*DIN + D)*DOUT + d] = sc[(h*DIN + D)*DOUT + d] * rs;
            cc[(h*DIN + D)*DOUT + d] = ccin[(h*DIN + D)*DOUT + d] * r2;
        }
        return;
    }
    const float* W = (row < 128) ? Wq : (row < 256) ? Wk : Wv;
    const float* bb = (row < 128) ? bq : (row < 256) ? bk : bv;
    int r = row & 127;
    Wc[(size_t)row*256 + t] = f2bf(W[(size_t)r*256 + t]);
    if (t == 0) bcat[row] = bb[r];
}

// ---------------------------------------------------------------- FoPE table fsc: [h][t][16] packed (fs lo16, fc hi16) bf16
__global__ __launch_bounds__(256) void k_tables(const float* __restrict__ inv, const float* __restrict__ cs,
                                                const float* __restrict__ cc,
                                                unsigned int* __restrict__ fsc)
{
    int t = threadIdx.x;
    int sub = t >> 6, lane = t & 63;
    int tpos = blockIdx.x*4 + sub;
    __shared__ float ssin[4][DIN], scos[4][DIN];
    if (lane < DIN) { float fr = (float)tpos * inv[lane]; ssin[sub][lane] = sinf(fr); scos[sub][lane] = cosf(fr); }
    __syncthreads();
    int h = lane >> 4, d = lane & 15;
    float as = 0.f, ac = 0.f;
    for (int D = 0; D < DIN; ++D) { as += ssin[sub][D]*cs[(h*DIN + D)*DOUT + d]; ac += scos[sub][D]*cc[(h*DIN + D)*DOUT + d]; }
    fsc[((size_t)h*NN + tpos)*16 + d] = ((unsigned int)f2bf(ac) << 16) | (unsigned int)f2bf(as);
}

// ---------------------------------------------------------------- QKV MFMA GEMM, T14 prefetch + LDS-staged epilogue
__global__ __launch_bounds__(256) void k_qkv_mfma(const float* __restrict__ x,
    const unsigned short* __restrict__ Wc, const float* __restrict__ bcat,
    float* __restrict__ q, float* __restrict__ k,
    unsigned short* __restrict__ qb, unsigned short* __restrict__ kb,
    unsigned short* __restrict__ vb)
{
    __shared__ __align__(16) char smem[32768];   // A: [0,16K) B: [16K,32K); epilogue: f32 [64][128]
    int t = threadIdx.x;
    int lin = blockIdx.y*3 + blockIdx.x;
    int logical = (lin & 7)*384 + (lin >> 3);
    int ntile = logical % 3;
    int mtile = logical / 3;
    int m0 = mtile * 128;
    int n0 = ntile * 128;
    int wave = t >> 6, lane = t & 63;
    int wm = wave >> 1, wn = wave & 1;
    int lrow = lane & 15, lk = lane >> 4;
    f32x4 acc[4][4];
    #pragma unroll
    for (int i = 0; i < 4; ++i)
        #pragma unroll
        for (int j = 0; j < 4; ++j) acc[i][j] = (f32x4){0.f,0.f,0.f,0.f};

    int am = t >> 4, ak4 = t & 15;
    size_t arow = (size_t)(m0 + am);
    float4 pa[8];
    #pragma unroll
    for (int p = 0; p < 8; ++p)
        pa[p] = *reinterpret_cast<const float4*>(&x[(arow + p*16)*256 + ak4*4]);

    #pragma unroll
    for (int kt = 0; kt < 4; ++kt) {
        int k0 = kt * 64;
        if (kt) __syncthreads();
        #pragma unroll
        for (int p = 0; p < 8; ++p) {
            int m = am + p*16;
            ushort4 b4;
            b4.x = f2bf(pa[p].x); b4.y = f2bf(pa[p].y); b4.z = f2bf(pa[p].z); b4.w = f2bf(pa[p].w);
            int byte = m*128 + ((ak4*8) ^ ((m & 7) << 4));
            *reinterpret_cast<ushort4*>(smem + byte) = b4;
        }
        {
            int n = t >> 3, k8 = t & 7;
            #pragma unroll
            for (int p = 0; p < 4; ++p, n += 32) {
                uint4 u4 = *reinterpret_cast<const uint4*>(&Wc[(size_t)(n0 + n)*256 + k0 + k8*8]);
                int byte = n*128 + ((k8 ^ (n & 7)) << 4);
                *reinterpret_cast<uint4*>(smem + 16384 + byte) = u4;
            }
        }
        if (kt < 3) {
            #pragma unroll
            for (int p = 0; p < 8; ++p)
                pa[p] = *reinterpret_cast<const float4*>(&x[(arow + p*16)*256 + (kt+1)*64 + ak4*4]);
        }
        __syncthreads();
        #pragma unroll
        for (int ks = 0; ks < 2; ++ks) {
            bf16x8 af[4], bfv[4];
            #pragma unroll
            for (int mi = 0; mi < 4; ++mi) {
                int m = wm*64 + mi*16 + lrow;
                int u = (ks*4 + lk) ^ (m & 7);
                af[mi] = *reinterpret_cast<const bf16x8*>(smem + m*128 + u*16);
            }
            #pragma unroll
            for (int ni = 0; ni < 4; ++ni) {
                int n = wn*64 + ni*16 + lrow;
                int u = (ks*4 + lk) ^ (n & 7);
                bfv[ni] = *reinterpret_cast<const bf16x8*>(smem + 16384 + n*128 + u*16);
            }
            #pragma unroll
            for (int mi = 0; mi < 4; ++mi)
                #pragma unroll
                for (int ni = 0; ni < 4; ++ni)
                    acc[mi][ni] = __builtin_amdgcn_mfma_f32_16x16x32_bf16(af[mi], bfv[ni], acc[mi][ni], 0, 0, 0);
        }
    }
    // LDS-staged epilogue: 2 chunks of 64 rows x 128 cols
    float* Cst = reinterpret_cast<float*>(smem);
    #pragma unroll
    for (int ch = 0; ch < 2; ++ch) {
        __syncthreads();
        if (wm == ch) {
            #pragma unroll
            for (int mi = 0; mi < 4; ++mi)
                #pragma unroll
                for (int ni = 0; ni < 4; ++ni) {
                    int col = wn*64 + ni*16 + lrow;
                    float bias = bcat[n0 + col];
                    #pragma unroll
                    for (int r = 0; r < 4; ++r) {
                        int rl = mi*16 + lk*4 + r;
                        Cst[rl*128 + col] = acc[mi][ni][r] + bias;
                    }
                }
        }
        __syncthreads();
        #pragma unroll
        for (int i = 0; i < 4; ++i) {
            int u = t + i*256;
            int row = u >> 4, c8 = u & 15;
            float4 va = *reinterpret_cast<const float4*>(&Cst[row*128 + c8*8]);
            float4 vb4 = *reinterpret_cast<const float4*>(&Cst[row*128 + c8*8 + 4]);
            size_t grow = (size_t)m0 + ch*64 + row;
            uint4 pk;
            pk.x = (unsigned)f2bf(va.x)  | ((unsigned)f2bf(va.y)  << 16);
            pk.y = (unsigned)f2bf(va.z)  | ((unsigned)f2bf(va.w)  << 16);
            pk.z = (unsigned)f2bf(vb4.x) | ((unsigned)f2bf(vb4.y) << 16);
            pk.w = (unsigned)f2bf(vb4.z) | ((unsigned)f2bf(vb4.w) << 16);
            if (ntile == 0) {
                *reinterpret_cast<float4*>(&q[grow*128 + c8*8])     = va;
                *reinterpret_cast<float4*>(&q[grow*128 + c8*8 + 4]) = vb4;
                *reinterpret_cast<uint4*>(&qb[grow*128 + c8*8])     = pk;
            } else if (ntile == 1) {
                *reinterpret_cast<float4*>(&k[grow*128 + c8*8])     = va;
                *reinterpret_cast<float4*>(&k[grow*128 + c8*8 + 4]) = vb4;
                *reinterpret_cast<uint4*>(&kb[grow*128 + c8*8])     = pk;
            } else {
                *reinterpret_cast<uint4*>(&vb[grow*128 + c8*8])     = pk;
            }
        }
    }
}

// ---------------------------------------------------------------- depthwise 3x3 LEPE conv, 8 ch/lane -> xspb bf16
__global__ __launch_bounds__(256) void k_conv(const unsigned short* __restrict__ vb, const float* __restrict__ w,
                                              const float* __restrict__ bias, unsigned short* __restrict__ xspb)
{
    __shared__ float wsmT[9][128];
    __shared__ float bsm[128];
    int t = threadIdx.x;
    for (int i = t; i < 1152; i += 256) wsmT[i % 9][i / 9] = w[i];
    if (t < 128) bsm[t] = bias[t];
    __syncthreads();
    int jj = t >> 4, c8 = (t & 15) * 8;
    int j = blockIdx.x * 16 + jj;
    int i = blockIdx.y, b = blockIdx.z;
    float acc[8];
    #pragma unroll
    for (int l = 0; l < 8; ++l) acc[l] = bsm[c8 + l];
    #pragma unroll
    for (int di = 0; di < 3; ++di) {
        int ii = i + di - 1;
        if (ii < 0 || ii >= 128) continue;
        #pragma unroll
        for (int dj = 0; dj < 3; ++dj) {
            int jx = j + dj - 1;
            if (jx < 0 || jx >= 128) continue;
            uint4 u = *reinterpret_cast<const uint4*>(&vb[((size_t)b*NN + ii*128 + jx)*128 + c8]);
            const unsigned short* us = (const unsigned short*)&u;
            int kk = di*3 + dj;
            #pragma unroll
            for (int l = 0; l < 8; ++l)
                acc[l] += wsmT[kk][c8 + l] * bf2f(us[l]);
        }
    }
    ushort4 r0, r1;
    r0.x = f2bf(acc[0]); r0.y = f2bf(acc[1]); r0.z = f2bf(acc[2]); r0.w = f2bf(acc[3]);
    r1.x = f2bf(acc[4]); r1.y = f2bf(acc[5]); r1.z = f2bf(acc[6]); r1.w = f2bf(acc[7]);
    size_t ob = ((size_t)b*NN + i*128 + j)*128 + c8;
    *reinterpret_cast<ushort4*>(&xspb[ob]) = r0;
    *reinterpret_cast<ushort4*>(&xspb[ob+4]) = r1;
}

// ---------------------------------------------------------------- fused k-features (MFMA) + kv partials (MFMA)
__global__ __launch_bounds__(256) void k_featkv(
    const unsigned short* __restrict__ kb, const unsigned short* __restrict__ vb,
    const float* __restrict__ W, const float* __restrict__ bvec,
    const unsigned int* __restrict__ fsc,
    float* __restrict__ kvpart, float* __restrict__ kmpart)
{
    __shared__ __align__(16) char smem[34816];
    __shared__ float kms[4][64];
    int bh = blockIdx.y, b = bh >> 2, h = bh & 3;
    int chunk = blockIdx.x;
    int t = threadIdx.x, w = t >> 6, lane = t & 63;
    int c = lane & 15, g = lane >> 4;
    unsigned short* kfsTw = reinterpret_cast<unsigned short*>(smem) + w*2560;
    unsigned short* vTw   = reinterpret_cast<unsigned short*>(smem + 20480) + w*1280;
    bf16x8 wb[2];
    #pragma unroll
    for (int et = 0; et < 2; ++et) {
        float4 wa = *reinterpret_cast<const float4*>(&W[(c + et*16)*32 + g*8]);
        float4 wb2 = *reinterpret_cast<const float4*>(&W[(c + et*16)*32 + g*8 + 4]);
        wb[et] = cvt8(wa, wb2);
    }
    float bias0 = bvec[c], bias1 = bvec[c + 16];
    f32x4 acc[4][2];
    #pragma unroll
    for (int i = 0; i < 4; ++i) { acc[i][0] = (f32x4){0.f,0.f,0.f,0.f}; acc[i][1] = (f32x4){0.f,0.f,0.f,0.f}; }
    f32x4 km0 = {0.f,0.f,0.f,0.f}, km1 = km0, km2 = km0, km3 = km0;

    for (int rnd = 0; rnd < 4; ++rnd) {
        int p0 = chunk*512 + w*128 + rnd*32;
        {
            uint4 vr0, vr1;
            size_t vbase = ((size_t)(b*NN + p0 + c*2))*128 + h*32 + g*8;
            vr0 = *reinterpret_cast<const uint4*>(&vb[vbase]);
            vr1 = *reinterpret_cast<const uint4*>(&vb[vbase + 128]);
            #pragma unroll
            for (int j = 0; j < 8; ++j) {
                ushort2 pk;
                pk.x = ((const unsigned short*)&vr0)[j];
                pk.y = ((const unsigned short*)&vr1)[j];
                *reinterpret_cast<ushort2*>(&vTw[(g*8 + j)*40 + c*2]) = pk;
            }
        }
        #pragma unroll
        for (int mt = 0; mt < 2; ++mt) {
            int posA = p0 + mt*16 + c;
            bf16x8 af = *reinterpret_cast<const bf16x8*>(&kb[((size_t)(b*NN + posA))*128 + h*32 + g*8]);
            f32x4 z4 = {0.f,0.f,0.f,0.f};
            f32x4 y0 = __builtin_amdgcn_mfma_f32_16x16x32_bf16(af, wb[0], z4, 0, 0, 0);
            f32x4 y1 = __builtin_amdgcn_mfma_f32_16x16x32_bf16(af, wb[1], z4, 0, 0, 0);
            f32x4 el0, eh0, el1, eh1;
            #pragma unroll
            for (int r = 0; r < 4; ++r) {
                float a0 = 2.f*(y0[r] + bias0);
                float a1 = 2.f*(y1[r] + bias1);
                el0[r] = __expf(a0); eh0[r] = __expf(-a0);
                el1[r] = __expf(a1); eh1[r] = __expf(-a1);
            }
            f32x4 s = el0 + eh0 + el1 + eh1;
            red16(s);
            f32x4 rs;
            #pragma unroll
            for (int r = 0; r < 4; ++r) rs[r] = rcpf(s[r]);
            f32x4 klo0 = el0*rs, khi0 = eh0*rs, klo1 = el1*rs, khi1 = eh1*rs;
            km0 += klo0; km1 += khi0; km2 += klo1; km3 += khi1;
            int posC = p0 + mt*16 + g*4;
            ushort4 wlo0, whi0, wlo1, whi1;
            #pragma unroll
            for (int r = 0; r < 4; ++r) {
                unsigned int u = fsc[((size_t)h*NN + posC + r)*16 + c];
                float fsv = bf2f((unsigned short)(u & 0xffffu));
                float fcv = bf2f((unsigned short)(u >> 16));
                ((unsigned short*)&wlo0)[r] = f2bf(klo0[r]*fcv + khi0[r]*fsv);
                ((unsigned short*)&whi0)[r] = f2bf(khi0[r]*fcv - klo0[r]*fsv);
                ((unsigned short*)&wlo1)[r] = f2bf(klo1[r] + khi1[r]);
                ((unsigned short*)&whi1)[r] = f2bf(khi1[r] - klo1[r]);
            }
            int po = mt*16 + g*4;
            *reinterpret_cast<ushort4*>(&kfsTw[(c)*40 + po])      = wlo0;
            *reinterpret_cast<ushort4*>(&kfsTw[(32 + c)*40 + po]) = whi0;
            *reinterpret_cast<ushort4*>(&kfsTw[(16 + c)*40 + po]) = wlo1;
            *reinterpret_cast<ushort4*>(&kfsTw[(48 + c)*40 + po]) = whi1;
        }
        {
            bf16x8 bf0 = *reinterpret_cast<const bf16x8*>(&vTw[(c)*40 + g*8]);
            bf16x8 bf1 = *reinterpret_cast<const bf16x8*>(&vTw[(16 + c)*40 + g*8]);
            #pragma unroll
            for (int mt = 0; mt < 4; ++mt) {
                bf16x8 af2 = *reinterpret_cast<const bf16x8*>(&kfsTw[(mt*16 + c)*40 + g*8]);
                acc[mt][0] = __builtin_amdgcn_mfma_f32_16x16x32_bf16(af2, bf0, acc[mt][0], 0, 0, 0);
                acc[mt][1] = __builtin_amdgcn_mfma_f32_16x16x32_bf16(af2, bf1, acc[mt][1], 0, 0, 0);
            }
        }
    }
    float kv0 = km0[0]+km0[1]+km0[2]+km0[3];
    float kv1 = km1[0]+km1[1]+km1[2]+km1[3];
    float kv2 = km2[0]+km2[1]+km2[2]+km2[3];
    float kv3 = km3[0]+km3[1]+km3[2]+km3[3];
    kv0 += __shfl_xor(kv0, 16); kv0 += __shfl_xor(kv0, 32);
    kv1 += __shfl_xor(kv1, 16); kv1 += __shfl_xor(kv1, 32);
    kv2 += __shfl_xor(kv2, 16); kv2 += __shfl_xor(kv2, 32);
    kv3 += __shfl_xor(kv3, 16); kv3 += __shfl_xor(kv3, 32);
    if (g == 0) {
        kms[w][c] = kv0; kms[w][16 + c] = kv2; kms[w][32 + c] = kv1; kms[w][48 + c] = kv3;
    }
    __syncthreads();
    float* kvred = reinterpret_cast<float*>(smem);
    #pragma unroll
    for (int mt = 0; mt < 4; ++mt)
        #pragma unroll
        for (int nt = 0; nt < 2; ++nt) {
            int d = nt*16 + c;
            *reinterpret_cast<f32x4*>(&kvred[(size_t)(w*32 + d)*68 + mt*16 + g*4]) = acc[mt][nt];
        }
    __syncthreads();
    #pragma unroll
    for (int i = 0; i < 8; ++i) {
        int idx = t*8 + i;
        int f = idx >> 5, d = idx & 31;
        float s2 = kvred[(0*32 + d)*68 + f] + kvred[(1*32 + d)*68 + f]
                 + kvred[(2*32 + d)*68 + f] + kvred[(3*32 + d)*68 + f];
        kvpart[((size_t)(bh*32 + chunk))*2048 + idx] = s2;
    }
    if (t < 64) {
        float s2 = kms[0][t] + kms[1][t] + kms[2][t] + kms[3][t];
        kmpart[(size_t)(bh*32 + chunk)*64 + t] = s2;
    }
}

// ---------------------------------------------------------------- reduce kv partials -> kvT bf16 [bh][d][f]; + kmean
__global__ __launch_bounds__(256) void k_kvred2(const float* __restrict__ kvpart, const float* __restrict__ kmpart,
                                                unsigned short* __restrict__ kvT, float* __restrict__ kmean)
{
    int bh = blockIdx.x >> 3, part = blockIdx.x & 7;
    int idx = part*256 + threadIdx.x;
    float s = 0.f;
    for (int cidx = 0; cidx < 32; ++cidx) s += kvpart[((size_t)(bh*32 + cidx))*2048 + idx];
    int f = idx >> 5, d = idx & 31;
    kvT[(size_t)bh*2048 + d*64 + f] = f2bf(s * (1.f/16384.f));
    if (part == 0 && threadIdx.x < 64) {
        int tt = threadIdx.x;
        float sm = 0.f;
        for (int cidx = 0; cidx < 32; ++cidx) sm += kmpart[(size_t)(bh*32 + cidx)*64 + tt];
        kmean[bh*64 + tt] = sm * (1.f/16384.f);
    }
}

// ---------------------------------------------------------------- fused q-features (MFMA) + xs (MFMA) -> xsb bf16
__global__ __launch_bounds__(256) void k_featxs(
    const unsigned short* __restrict__ qb, const float* __restrict__ W, const float* __restrict__ bvec,
    const unsigned int* __restrict__ fsc, const unsigned short* __restrict__ kvT,
    const float* __restrict__ kmean, const unsigned short* __restrict__ xspb, unsigned short* __restrict__ xsb)
{
    __shared__ __align__(16) unsigned short qfs[4][32][72];
    int bh = blockIdx.y, b = bh >> 2, h = bh & 3;
    int chunk = blockIdx.x;
    int t = threadIdx.x, w = t >> 6, lane = t & 63;
    int c = lane & 15, g = lane >> 4;
    bf16x8 wb[2];
    #pragma unroll
    for (int et = 0; et < 2; ++et) {
        float4 wa = *reinterpret_cast<const float4*>(&W[(c + et*16)*32 + g*8]);
        float4 wb2 = *reinterpret_cast<const float4*>(&W[(c + et*16)*32 + g*8 + 4]);
        wb[et] = cvt8(wa, wb2);
    }
    float bias0 = bvec[c], bias1 = bvec[c + 16];
    float kml0 = kmean[bh*64 + c],      kml1 = kmean[bh*64 + 16 + c];
    float kmh0 = kmean[bh*64 + 32 + c], kmh1 = kmean[bh*64 + 48 + c];
    bf16x8 bkv[2][2];
    #pragma unroll
    for (int nt = 0; nt < 2; ++nt)
        #pragma unroll
        for (int ks = 0; ks < 2; ++ks)
            bkv[nt][ks] = *reinterpret_cast<const bf16x8*>(&kvT[(size_t)bh*2048 + (nt*16 + c)*64 + ks*32 + g*8]);

    for (int rnd = 0; rnd < 4; ++rnd) {
        int p0 = chunk*512 + w*128 + rnd*32;
        #pragma unroll
        for (int mt = 0; mt < 2; ++mt) {
            int posA = p0 + mt*16 + c;
            bf16x8 af = *reinterpret_cast<const bf16x8*>(&qb[((size_t)(b*NN + posA))*128 + h*32 + g*8]);
            f32x4 z4 = {0.f,0.f,0.f,0.f};
            f32x4 y0 = __builtin_amdgcn_mfma_f32_16x16x32_bf16(af, wb[0], z4, 0, 0, 0);
            f32x4 y1 = __builtin_amdgcn_mfma_f32_16x16x32_bf16(af, wb[1], z4, 0, 0, 0);
            f32x4 el0, eh0, el1, eh1;
            #pragma unroll
            for (int r = 0; r < 4; ++r) {
                float a0 = 2.f*(y0[r] + bias0);
                float a1 = 2.f*(y1[r] + bias1);
                el0[r] = __expf(a0); eh0[r] = __expf(-a0);
                el1[r] = __expf(a1); eh1[r] = __expf(-a1);
            }
            f32x4 s = el0 + eh0 + el1 + eh1;
            f32x4 wv = el0*kml0 + eh0*kmh0 + el1*kml1 + eh1*kmh1;
            red16x2(s, wv);
            f32x4 zr;
            #pragma unroll
            for (int r = 0; r < 4; ++r) {
                float rs = rcpf(s[r]);
                float z = rcpf(wv[r]*rs + 1e-6f);
                zr[r] = z*rs;
            }
            int posC = mt*16 + g*4;
            #pragma unroll
            for (int r = 0; r < 4; ++r) {
                unsigned int u = fsc[((size_t)h*NN + p0 + posC + r)*16 + c];
                float fsv = bf2f((unsigned short)(u & 0xffffu));
                float fcv = bf2f((unsigned short)(u >> 16));
                qfs[w][posC + r][c]      = f2bf(zr[r]*(el0[r]*fcv + eh0[r]*fsv));
                qfs[w][posC + r][32 + c] = f2bf(zr[r]*(eh0[r]*fcv - el0[r]*fsv));
                qfs[w][posC + r][16 + c] = f2bf(zr[r]*(el1[r] + eh1[r]));
                qfs[w][posC + r][48 + c] = f2bf(zr[r]*(eh1[r] - el1[r]));
            }
        }
        f32x4 acc[2][2];
        #pragma unroll
        for (int i = 0; i < 2; ++i) { acc[i][0] = (f32x4){0.f,0.f,0.f,0.f}; acc[i][1] = (f32x4){0.f,0.f,0.f,0.f}; }
        #pragma unroll
        for (int ks = 0; ks < 2; ++ks)
            #pragma unroll
            for (int mt = 0; mt < 2; ++mt) {
                bf16x8 af2 = *reinterpret_cast<const bf16x8*>(&qfs[w][mt*16 + c][ks*32 + g*8]);
                acc[mt][0] = __builtin_amdgcn_mfma_f32_16x16x32_bf16(af2, bkv[0][ks], acc[mt][0], 0, 0, 0);
                acc[mt][1] = __builtin_amdgcn_mfma_f32_16x16x32_bf16(af2, bkv[1][ks], acc[mt][1], 0, 0, 0);
            }
        #pragma unroll
        for (int mt = 0; mt < 2; ++mt)
            #pragma unroll
            for (int nt = 0; nt < 2; ++nt) {
                int d = nt*16 + c;
                #pragma unroll
                for (int r = 0; r < 4; ++r) {
                    int pos = p0 + mt*16 + g*4 + r;
                    size_t off = ((size_t)(b*NN + pos))*128 + h*32 + d;
                    xsb[off] = f2bf(bf2f(xspb[off]) + acc[mt][nt][r]);
                }
            }
    }
}

// ---------------------------------------------------------------- gram via MFMA + fused norms
__global__ __launch_bounds__(256) void k_gram(const unsigned short* __restrict__ qb, const unsigned short* __restrict__ kb,
                                              float* __restrict__ Gpart,
                                              float* __restrict__ qn2, float* __restrict__ kn2)
{
    __shared__ unsigned short qTs[128][40];
    __shared__ unsigned short kTs[128][40];
    int kc = blockIdx.x, bb = blockIdx.y;
    int t = threadIdx.x, lane = t & 63;
    int wave = t >> 6, wm = wave >> 1, wn = wave & 1;
    int c = t & 127, lh = t >> 7;
    float qa = 0.f, ka = 0.f;
    f32x4 acc[4][4];
    #pragma unroll
    for (int i = 0; i < 4; ++i)
        #pragma unroll
        for (int j = 0; j < 4; ++j) acc[i][j] = (f32x4){0.f,0.f,0.f,0.f};

    for (int kt = 0; kt < 8; ++kt) {
        __syncthreads();
        #pragma unroll
        for (int i = 0; i < 16; ++i) {
            int l = lh*16 + i;
            size_t pos = (size_t)bb*NN + kc*256 + kt*32 + l;
            unsigned short qu = qb[pos*128 + c];
            unsigned short ku = kb[pos*128 + c];
            float qv = bf2f(qu), kvv = bf2f(ku);
            qa += qv*qv; ka += kvv*kvv;
            qTs[c][l] = qu;
            kTs[c][l] = ku;
        }
        __syncthreads();
        bf16x8 af[4];
        #pragma unroll
        for (int mi = 0; mi < 4; ++mi)
            af[mi] = *reinterpret_cast<const bf16x8*>(&qTs[wm*64 + mi*16 + (lane & 15)][(lane >> 4)*8]);
        #pragma unroll
        for (int ni = 0; ni < 4; ++ni) {
            bf16x8 bfr = *reinterpret_cast<const bf16x8*>(&kTs[wn*64 + ni*16 + (lane & 15)][(lane >> 4)*8]);
            #pragma unroll
            for (int mi = 0; mi < 4; ++mi)
                acc[mi][ni] = __builtin_amdgcn_mfma_f32_16x16x32_bf16(af[mi], bfr, acc[mi][ni], 0, 0, 0);
        }
    }
    size_t gb = ((size_t)(bb*64 + kc))*16384;
    #pragma unroll
    for (int mi = 0; mi < 4; ++mi) {
        #pragma unroll
        for (int ni = 0; ni < 4; ++ni) {
            int d = wn*64 + ni*16 + (lane & 15);
            #pragma unroll
            for (int r = 0; r < 4; ++r) {
                int cc = wm*64 + mi*16 + (lane >> 4)*4 + r;
                Gpart[gb + (size_t)cc*128 + d] = acc[mi][ni][r];
            }
        }
    }
    atomicAdd(&qn2[bb*128 + c], qa);
    atomicAdd(&kn2[bb*128 + c], ka);
}

// ---------------------------------------------------------------- channel attention softmax (fused Gpart reduction)
__global__ __launch_bounds__(128) void k_attnsm(const float* __restrict__ Gpart, const float* __restrict__ qn2,
    const float* __restrict__ kn2, const float* __restrict__ temp, float* __restrict__ attn)
{
    __shared__ float red[128];
    int row = blockIdx.x;
    int b = row >> 7, c = row & 127;
    int t = threadIdx.x;
    float s0 = 0.f;
    for (int kc = 0; kc < 64; ++kc)
        s0 += Gpart[((size_t)(b*64 + kc))*16384 + (size_t)c*128 + t];
    float qn = fmaxf(sqrtf(qn2[b*128 + c]), 1e-12f);
    float kn = fmaxf(sqrtf(kn2[b*128 + t]), 1e-12f);
    float val = s0 / (qn*kn) * temp[c];
    red[t] = val; __syncthreads();
    for (int s = 64; s > 0; s >>= 1) { if (t < s) red[t] = fmaxf(red[t], red[t+s]); __syncthreads(); }
    float mm = red[0]; __syncthreads();
    float ev = expf(val - mm);
    red[t] = ev; __syncthreads();
    for (int s = 64; s > 0; s >>= 1) { if (t < s) red[t] += red[t+s]; __syncthreads(); }
    attn[(size_t)row*128 + t] = ev / red[0];
}

// ---------------------------------------------------------------- per-batch B matrix, transposed bf16
__global__ __launch_bounds__(256) void k_bmat(const float* __restrict__ attn, const float* __restrict__ Wp,
                                              unsigned short* __restrict__ BmatT)
{
    int b = blockIdx.y, kk = blockIdx.x, o = threadIdx.x;
    float val;
    if (kk < 128) {
        val = Wp[(size_t)o*256 + kk];
    } else {
        int d = kk - 128;
        __shared__ float a[128];
        if (o < 128) a[o] = attn[((size_t)b*128 + o)*128 + d];
        __syncthreads();
        float acc = 0.f;
        for (int c = 0; c < 128; ++c) acc += a[c] * Wp[(size_t)o*256 + 128 + c];
        val = acc;
    }
    BmatT[((size_t)b*256 + o)*256 + kk] = f2bf(val);
}

// ---------------------------------------------------------------- final MFMA GEMM, T14 prefetch + LDS-staged epilogue
__global__ __launch_bounds__(256) void k_out_mfma(const unsigned short* __restrict__ xsb,
    const unsigned short* __restrict__ vb, const unsigned short* __restrict__ BmatT,
    const float* __restrict__ bp, float* __restrict__ out)
{
    __shared__ __align__(16) char smem[32768];
    int t = threadIdx.x;
    int lin = blockIdx.y*2 + blockIdx.x;
    int logical = (lin & 7)*256 + (lin >> 3);
    int ntile = logical & 1;
    int mtile = logical >> 1;
    int m0 = mtile * 128;
    int n0 = ntile * 128;
    int b = mtile >> 7;
    int wave = t >> 6, lane = t & 63;
    int wm = wave >> 1, wn = wave & 1;
    int lrow = lane & 15, lk = lane >> 4;
    f32x4 acc[4][4];
    #pragma unroll
    for (int i = 0; i < 4; ++i)
        #pragma unroll
        for (int j = 0; j < 4; ++j) acc[i][j] = (f32x4){0.f,0.f,0.f,0.f};

    int am = t >> 3, ak8 = t & 7;
    uint4 pa4[4];
    #pragma unroll
    for (int p = 0; p < 4; ++p)
        pa4[p] = *reinterpret_cast<const uint4*>(&xsb[(size_t)(m0 + am + p*32)*128 + ak8*8]);

    #pragma unroll
    for (int kt = 0; kt < 4; ++kt) {
        if (kt) __syncthreads();
        #pragma unroll
        for (int p = 0; p < 4; ++p) {
            int m = am + p*32;
            int byte = m*128 + ((ak8 ^ (m & 7)) << 4);
            *reinterpret_cast<uint4*>(smem + byte) = pa4[p];
        }
        {
            int n = t >> 3, k8 = t & 7;
            #pragma unroll
            for (int p = 0; p < 4; ++p, n += 32) {
                uint4 u4 = *reinterpret_cast<const uint4*>(&BmatT[((size_t)b*256 + n0 + n)*256 + kt*64 + k8*8]);
                int byte = n*128 + ((k8 ^ (n & 7)) << 4);
                *reinterpret_cast<uint4*>(smem + 16384 + byte) = u4;
            }
        }
        if (kt < 3) {
            const unsigned short* Asrc = ((kt+1) < 2) ? xsb : vb;
            int ka0 = ((kt+1) & 1) * 64;
            #pragma unroll
            for (int p = 0; p < 4; ++p)
                pa4[p] = *reinterpret_cast<const uint4*>(&Asrc[(size_t)(m0 + am + p*32)*128 + ka0 + ak8*8]);
        }
        __syncthreads();
        #pragma unroll
        for (int ks = 0; ks < 2; ++ks) {
            bf16x8 af[4], bfv[4];
            #pragma unroll
            for (int mi = 0; mi < 4; ++mi) {
                int m = wm*64 + mi*16 + lrow;
                int u = (ks*4 + lk) ^ (m & 7);
                af[mi] = *reinterpret_cast<const bf16x8*>(smem + m*128 + u*16);
            }
            #pragma unroll
            for (int ni = 0; ni < 4; ++ni) {
                int n = wn*64 + ni*16 + lrow;
                int u = (ks*4 + lk) ^ (n & 7);
                bfv[ni] = *reinterpret_cast<const bf16x8*>(smem + 16384 + n*128 + u*16);
            }
            #pragma unroll
            for (int mi = 0; mi < 4; ++mi)
                #pragma unroll
                for (int ni = 0; ni < 4; ++ni)
                    acc[mi][ni] = __builtin_amdgcn_mfma_f32_16x16x32_bf16(af[mi], bfv[ni], acc[mi][ni], 0, 0, 0);
        }
    }
    // LDS-staged epilogue: 2 chunks of 64 rows x 128 cols
    float* Cst = reinterpret_cast<float*>(smem);
    #pragma unroll
    for (int ch = 0; ch < 2; ++ch) {
        __syncthreads();
        if (wm == ch) {
            #pragma unroll
            for (int mi = 0; mi < 4; ++mi)
                #pragma unroll
                for (int ni = 0; ni < 4; ++ni) {
                    int col = wn*64 + ni*16 + lrow;
                    float bias = bp[n0 + col];
                    #pragma unroll
                    for (int r = 0; r < 4; ++r) {
                        int rl = mi*16 + lk*4 + r;
                        Cst[rl*128 + col] = acc[mi][ni][r] + bias;
                    }
                }
        }
        __syncthreads();
        #pragma unroll
        for (int i = 0; i < 4; ++i) {
            int u = t + i*256;
            int row = u >> 4, c8 = u & 15;
            float4 va = *reinterpret_cast<const float4*>(&Cst[row*128 + c8*8]);
            float4 vb4 = *reinterpret_cast<const float4*>(&Cst[row*128 + c8*8 + 4]);
            size_t grow = (size_t)m0 + ch*64 + row;
            *reinterpret_cast<float4*>(&out[grow*256 + n0 + c8*8])     = va;
            *reinterpret_cast<float4*>(&out[grow*256 + n0 + c8*8 + 4]) = vb4;
        }
    }
}

extern "C" void kernel_launch(void* const* d_in, const int* in_sizes, int n_in,
                              void* d_out, int out_size, void* d_ws, size_t ws_size,
                              hipStream_t stream)
{
    (void)in_sizes; (void)n_in; (void)out_size; (void)ws_size;
    const float* x    = (const float*)d_in[0];
    const float* Wq   = (const float*)d_in[1];
    const float* bq   = (const float*)d_in[2];
    const float* Wk   = (const float*)d_in[3];
    const float* bk   = (const float*)d_in[4];
    const float* Wv   = (const float*)d_in[5];
    const float* bv   = (const float*)d_in[6];
    const float* Whq  = (const float*)d_in[7];
    const float* bhq  = (const float*)d_in[8];
    const float* Whk  = (const float*)d_in[9];
    const float* bhk  = (const float*)d_in[10];
    const float* sinc = (const float*)d_in[11];
    const float* cosc = (const float*)d_in[12];
    const float* lw   = (const float*)d_in[13];
    const float* lb   = (const float*)d_in[14];
    const float* temp = (const float*)d_in[15];
    const float* Wp   = (const float*)d_in[16];
    const float* bp   = (const float*)d_in[17];

    float* out = (float*)d_out;
    float* q   = out + 33554432;
    float* k   = out + 50331648;
    float* ws  = (float*)d_ws;

    unsigned short* xspb = (unsigned short*)(ws + WS_XSPB);
    float* Gpart  = ws + WS_GPART;
    unsigned short* vbuf = (unsigned short*)(ws + WS_VB);
    unsigned short* xsb  = (unsigned short*)(ws + WS_XSB);
    unsigned int* fsc = (unsigned int*)(ws + WS_FS);
    float* inv    = ws + WS_INV;
    float* cs     = ws + WS_CS;
    float* cc     = ws + WS_CC;
    unsigned short* Wc = (unsigned short*)(ws + WS_WCAT);
    float* bcat   = ws + WS_BCAT;
    float* kvpart = ws + WS_KVPART;
    float* kmpart = ws + WS_KMPART;
    unsigned short* kvT = (unsigned short*)(ws + WS_KV);
    float* kmean  = ws + WS_KMEAN;
    float* qn2    = ws + WS_QN2;
    float* kn2    = ws + WS_KN2;
    float* attn   = ws + WS_ATTN;
    unsigned short* BmatT = (unsigned short*)(ws + WS_BMATT);
    unsigned short* qbuf  = (unsigned short*)(ws + WS_QB);
    unsigned short* kbuf  = (unsigned short*)(ws + WS_KB);

    hipMemsetAsync(qn2, 0, 2048*sizeof(float), stream);

    k_wprep<<<385, 256, 0, stream>>>(Wq, Wk, Wv, bq, bk, bv, sinc, cosc, Wc, bcat, inv, cs, cc);
    k_tables<<<4096, 256, 0, stream>>>(inv, cs, cc, fsc);
    k_qkv_mfma<<<dim3(3, 1024), 256, 0, stream>>>(x, Wc, bcat, q, k, qbuf, kbuf, vbuf);
    k_conv<<<dim3(8, 128, 8), 256, 0, stream>>>(vbuf, lw, lb, xspb);
    k_featkv<<<dim3(32, 32), 256, 0, stream>>>(kbuf, vbuf, Whk, bhk, fsc, kvpart, kmpart);
    k_kvred2<<<256, 256, 0, stream>>>(kvpart, kmpart, kvT, kmean);
    k_featxs<<<dim3(32, 32), 256, 0, stream>>>(qbuf, Whq, bhq, fsc, kvT, kmean, xspb, xsb);
    k_gram<<<dim3(64, 8), 256, 0, stream>>>(qbuf, kbuf, Gpart, qn2, kn2);
    k_attnsm<<<1024, 128, 0, stream>>>(Gpart, qn2, kn2, temp, attn);
    k_bmat<<<dim3(256, 8), 256, 0, stream>>>(attn, Wp, BmatT);
    k_out_mfma<<<dim3(2, 1024), 256, 0, stream>>>(xsb, vbuf, BmatT, bp, out);
}

// Round 12
// 367.469 us; speedup vs baseline: 1.2788x; 1.2788x over previous
//
#include <hip/hip_runtime.h>
#include <cmath>

#define NB 8
#define NN 16384
#define DIN 23
#define DOUT 16

typedef short bf16x8 __attribute__((ext_vector_type(8)));
typedef float f32x4 __attribute__((ext_vector_type(4)));

__device__ __forceinline__ unsigned short f2bf(float f) {
    unsigned int u = __float_as_uint(f);
    u += 0x7FFFu + ((u >> 16) & 1u);
    return (unsigned short)(u >> 16);
}
__device__ __forceinline__ float bf2f(unsigned short s) {
    return __uint_as_float(((unsigned int)s) << 16);
}
__device__ __forceinline__ float rcpf(float x) { return __builtin_amdgcn_rcpf(x); }

__device__ __forceinline__ bf16x8 cvt8(float4 a, float4 b) {
    bf16x8 r;
    r[0]=(short)f2bf(a.x); r[1]=(short)f2bf(a.y); r[2]=(short)f2bf(a.z); r[3]=(short)f2bf(a.w);
    r[4]=(short)f2bf(b.x); r[5]=(short)f2bf(b.y); r[6]=(short)f2bf(b.z); r[7]=(short)f2bf(b.w);
    return r;
}
__device__ __forceinline__ void red16(f32x4& s) {
    #pragma unroll
    for (int off = 1; off < 16; off <<= 1) {
        s[0] += __shfl_xor(s[0], off); s[1] += __shfl_xor(s[1], off);
        s[2] += __shfl_xor(s[2], off); s[3] += __shfl_xor(s[3], off);
    }
}
__device__ __forceinline__ void red16x2(f32x4& s, f32x4& w) {
    #pragma unroll
    for (int off = 1; off < 16; off <<= 1) {
        s[0] += __shfl_xor(s[0], off); s[1] += __shfl_xor(s[1], off);
        s[2] += __shfl_xor(s[2], off); s[3] += __shfl_xor(s[3], off);
        w[0] += __shfl_xor(w[0], off); w[1] += __shfl_xor(w[1], off);
        w[2] += __shfl_xor(w[2], off); w[3] += __shfl_xor(w[3], off);
    }
}

// workspace offsets in floats
#define WS_XSPB   ((size_t)0)
#define WS_GPART  ((size_t)8388608)
#define WS_VB     ((size_t)16777216)
#define WS_XSB    ((size_t)25165824)
#define WS_FS     ((size_t)33554432)
#define WS_INV    ((size_t)35651584)
#define WS_CS     ((size_t)35651648)
#define WS_CC     ((size_t)35653184)
#define WS_WCAT   ((size_t)35654720)
#define WS_BCAT   ((size_t)35703872)
#define WS_KVPART ((size_t)35704256)
#define WS_KMPART ((size_t)37801408)
#define WS_KV     ((size_t)37866944)
#define WS_KMEAN  ((size_t)37932480)
#define WS_QN2    ((size_t)37934528)
#define WS_KN2    ((size_t)37935552)
#define WS_ATTN   ((size_t)38067648)
#define WS_BMATT  ((size_t)38198720)
#define WS_QB     ((size_t)38460864)
#define WS_KB     ((size_t)46849472)

// ---------------------------------------------------------------- weights prep + setup (merged)
__global__ __launch_bounds__(256) void k_wprep(
    const float* __restrict__ Wq, const float* __restrict__ Wk, const float* __restrict__ Wv,
    const float* __restrict__ bq, const float* __restrict__ bk, const float* __restrict__ bv,
    const float* __restrict__ sc, const float* __restrict__ ccin,
    unsigned short* __restrict__ Wc, float* __restrict__ bcat,
    float* __restrict__ inv, float* __restrict__ cs, float* __restrict__ cc)
{
    int row = blockIdx.x, t = threadIdx.x;
    if (row == 384) {
        if (t >= 64) return;
        if (t < DIN) inv[t] = (float)pow(10000.0, -((double)(2 * t)) / 64.0);
        int h = t >> 4, d = t & 15;
        float ss = 0.f, s2 = 0.f;
        for (int D = 0; D < DIN; ++D) { ss += sc[(h*DIN + D)*DOUT + d]; s2 += ccin[(h*DIN + D)*DOUT + d]; }
        float rs = 1.f / ss, r2 = 1.f / s2;
        for (int D = 0; D < DIN; ++D) {
            cs[(h*DIN + D)*DOUT + d] = sc[(h*DIN + D)*DOUT + d] * rs;
            cc[(h*DIN + D)*DOUT + d] = ccin[(h*DIN + D)*DOUT + d] * r2;
        }
        return;
    }
    const float* W = (row < 128) ? Wq : (row < 256) ? Wk : Wv;
    const float* bb = (row < 128) ? bq : (row < 256) ? bk : bv;
    int r = row & 127;
    Wc[(size_t)row*256 + t] = f2bf(W[(size_t)r*256 + t]);
    if (t == 0) bcat[row] = bb[r];
}

// ---------------------------------------------------------------- FoPE table fsc
__global__ __launch_bounds__(256) void k_tables(const float* __restrict__ inv, const float* __restrict__ cs,
                                                const float* __restrict__ cc,
                                                unsigned int* __restrict__ fsc)
{
    int t = threadIdx.x;
    int sub = t >> 6, lane = t & 63;
    int tpos = blockIdx.x*4 + sub;
    __shared__ float ssin[4][DIN], scos[4][DIN];
    if (lane < DIN) { float fr = (float)tpos * inv[lane]; ssin[sub][lane] = sinf(fr); scos[sub][lane] = cosf(fr); }
    __syncthreads();
    int h = lane >> 4, d = lane & 15;
    float as = 0.f, ac = 0.f;
    for (int D = 0; D < DIN; ++D) { as += ssin[sub][D]*cs[(h*DIN + D)*DOUT + d]; ac += scos[sub][D]*cc[(h*DIN + D)*DOUT + d]; }
    fsc[((size_t)h*NN + tpos)*16 + d] = ((unsigned int)f2bf(ac) << 16) | (unsigned int)f2bf(as);
}

// ---------------------------------------------------------------- QKV MFMA GEMM: BM=128 x BN=384 (q|k|v fused), 8 waves
__global__ __launch_bounds__(512) void k_qkv_mfma(const float* __restrict__ x,
    const unsigned short* __restrict__ Wc, const float* __restrict__ bcat,
    float* __restrict__ q, float* __restrict__ k,
    unsigned short* __restrict__ qb, unsigned short* __restrict__ kb,
    unsigned short* __restrict__ vb)
{
    __shared__ __align__(16) char smem[65536];   // A: [0,16K) bf16 128x64 swz; B: [16K,64K) bf16 384x64 swz
    int t = threadIdx.x;
    int lin = blockIdx.x;
    int mtile = (lin & 7)*128 + (lin >> 3);      // 1024 % 8 == 0, bijective XCD swizzle
    int m0 = mtile * 128;
    int wave = t >> 6, lane = t & 63;
    int wm = wave >> 2, wn = wave & 3;           // 2M x 4N
    int lrow = lane & 15, lk = lane >> 4;
    f32x4 acc[4][6];
    #pragma unroll
    for (int i = 0; i < 4; ++i)
        #pragma unroll
        for (int j = 0; j < 6; ++j) acc[i][j] = (f32x4){0.f,0.f,0.f,0.f};

    int am = t >> 4, ak4 = t & 15;               // am 0..31, 4 passes of 32 rows
    size_t arow = (size_t)(m0 + am);
    float4 pa[4];
    #pragma unroll
    for (int p = 0; p < 4; ++p)
        pa[p] = *reinterpret_cast<const float4*>(&x[(arow + p*32)*256 + ak4*4]);

    #pragma unroll
    for (int kt = 0; kt < 4; ++kt) {
        int k0 = kt * 64;
        if (kt) __syncthreads();
        // A: ds_write from prefetched regs (f32->bf16, swizzled)
        #pragma unroll
        for (int p = 0; p < 4; ++p) {
            int m = am + p*32;
            ushort4 b4;
            b4.x = f2bf(pa[p].x); b4.y = f2bf(pa[p].y); b4.z = f2bf(pa[p].z); b4.w = f2bf(pa[p].w);
            int byte = m*128 + ((ak4*8) ^ ((m & 7) << 4));
            *reinterpret_cast<ushort4*>(smem + byte) = b4;
        }
        // B: 384 rows x 64 k (Wc L2-hot)
        {
            int n = t >> 3, k8 = t & 7;
            #pragma unroll
            for (int p = 0; p < 6; ++p, n += 64) {
                uint4 u4 = *reinterpret_cast<const uint4*>(&Wc[(size_t)n*256 + k0 + k8*8]);
                int byte = n*128 + ((k8 ^ (n & 7)) << 4);
                *reinterpret_cast<uint4*>(smem + 16384 + byte) = u4;
            }
        }
        // prefetch next A k-slice (in flight across barrier + MFMA)
        if (kt < 3) {
            #pragma unroll
            for (int p = 0; p < 4; ++p)
                pa[p] = *reinterpret_cast<const float4*>(&x[(arow + p*32)*256 + (kt+1)*64 + ak4*4]);
        }
        __syncthreads();
        #pragma unroll
        for (int ks = 0; ks < 2; ++ks) {
            bf16x8 af[4];
            #pragma unroll
            for (int mi = 0; mi < 4; ++mi) {
                int m = wm*64 + mi*16 + lrow;
                int u = (ks*4 + lk) ^ (m & 7);
                af[mi] = *reinterpret_cast<const bf16x8*>(smem + m*128 + u*16);
            }
            #pragma unroll
            for (int ni = 0; ni < 6; ++ni) {
                int n = wn*96 + ni*16 + lrow;
                int u = (ks*4 + lk) ^ (n & 7);
                bf16x8 bfv = *reinterpret_cast<const bf16x8*>(smem + 16384 + n*128 + u*16);
                #pragma unroll
                for (int mi = 0; mi < 4; ++mi)
                    acc[mi][ni] = __builtin_amdgcn_mfma_f32_16x16x32_bf16(af[mi], bfv, acc[mi][ni], 0, 0, 0);
            }
        }
    }
    // epilogue: direct stores (proven faster than LDS staging)
    #pragma unroll
    for (int mi = 0; mi < 4; ++mi) {
        #pragma unroll
        for (int ni = 0; ni < 6; ++ni) {
            int gcol = wn*96 + ni*16 + lrow;
            int c = gcol & 127;
            float bias = bcat[gcol];
            #pragma unroll
            for (int r = 0; r < 4; ++r) {
                size_t grow = (size_t)m0 + wm*64 + mi*16 + lk*4 + r;
                float val = acc[mi][ni][r] + bias;
                if (gcol < 128)      { q[grow*128 + c] = val; qb[grow*128 + c] = f2bf(val); }
                else if (gcol < 256) { k[grow*128 + c] = val; kb[grow*128 + c] = f2bf(val); }
                else                 vb[grow*128 + c] = f2bf(val);
            }
        }
    }
}

// ---------------------------------------------------------------- depthwise 3x3 LEPE conv, 8 ch/lane -> xspb bf16
__global__ __launch_bounds__(256) void k_conv(const unsigned short* __restrict__ vb, const float* __restrict__ w,
                                              const float* __restrict__ bias, unsigned short* __restrict__ xspb)
{
    __shared__ float wsmT[9][128];
    __shared__ float bsm[128];
    int t = threadIdx.x;
    for (int i = t; i < 1152; i += 256) wsmT[i % 9][i / 9] = w[i];
    if (t < 128) bsm[t] = bias[t];
    __syncthreads();
    int jj = t >> 4, c8 = (t & 15) * 8;
    int j = blockIdx.x * 16 + jj;
    int i = blockIdx.y, b = blockIdx.z;
    float acc[8];
    #pragma unroll
    for (int l = 0; l < 8; ++l) acc[l] = bsm[c8 + l];
    #pragma unroll
    for (int di = 0; di < 3; ++di) {
        int ii = i + di - 1;
        if (ii < 0 || ii >= 128) continue;
        #pragma unroll
        for (int dj = 0; dj < 3; ++dj) {
            int jx = j + dj - 1;
            if (jx < 0 || jx >= 128) continue;
            uint4 u = *reinterpret_cast<const uint4*>(&vb[((size_t)b*NN + ii*128 + jx)*128 + c8]);
            const unsigned short* us = (const unsigned short*)&u;
            int kk = di*3 + dj;
            #pragma unroll
            for (int l = 0; l < 8; ++l)
                acc[l] += wsmT[kk][c8 + l] * bf2f(us[l]);
        }
    }
    ushort4 r0, r1;
    r0.x = f2bf(acc[0]); r0.y = f2bf(acc[1]); r0.z = f2bf(acc[2]); r0.w = f2bf(acc[3]);
    r1.x = f2bf(acc[4]); r1.y = f2bf(acc[5]); r1.z = f2bf(acc[6]); r1.w = f2bf(acc[7]);
    size_t ob = ((size_t)b*NN + i*128 + j)*128 + c8;
    *reinterpret_cast<ushort4*>(&xspb[ob]) = r0;
    *reinterpret_cast<ushort4*>(&xspb[ob+4]) = r1;
}

// ---------------------------------------------------------------- fused k-features (MFMA) + kv partials (MFMA)
__global__ __launch_bounds__(256) void k_featkv(
    const unsigned short* __restrict__ kb, const unsigned short* __restrict__ vb,
    const float* __restrict__ W, const float* __restrict__ bvec,
    const unsigned int* __restrict__ fsc,
    float* __restrict__ kvpart, float* __restrict__ kmpart)
{
    __shared__ __align__(16) char smem[34816];
    __shared__ float kms[4][64];
    int bh = blockIdx.y, b = bh >> 2, h = bh & 3;
    int chunk = blockIdx.x;
    int t = threadIdx.x, w = t >> 6, lane = t & 63;
    int c = lane & 15, g = lane >> 4;
    unsigned short* kfsTw = reinterpret_cast<unsigned short*>(smem) + w*2560;
    unsigned short* vTw   = reinterpret_cast<unsigned short*>(smem + 20480) + w*1280;
    bf16x8 wb[2];
    #pragma unroll
    for (int et = 0; et < 2; ++et) {
        float4 wa = *reinterpret_cast<const float4*>(&W[(c + et*16)*32 + g*8]);
        float4 wb2 = *reinterpret_cast<const float4*>(&W[(c + et*16)*32 + g*8 + 4]);
        wb[et] = cvt8(wa, wb2);
    }
    float bias0 = bvec[c], bias1 = bvec[c + 16];
    f32x4 acc[4][2];
    #pragma unroll
    for (int i = 0; i < 4; ++i) { acc[i][0] = (f32x4){0.f,0.f,0.f,0.f}; acc[i][1] = (f32x4){0.f,0.f,0.f,0.f}; }
    f32x4 km0 = {0.f,0.f,0.f,0.f}, km1 = km0, km2 = km0, km3 = km0;

    for (int rnd = 0; rnd < 4; ++rnd) {
        int p0 = chunk*512 + w*128 + rnd*32;
        {
            uint4 vr0, vr1;
            size_t vbase = ((size_t)(b*NN + p0 + c*2))*128 + h*32 + g*8;
            vr0 = *reinterpret_cast<const uint4*>(&vb[vbase]);
            vr1 = *reinterpret_cast<const uint4*>(&vb[vbase + 128]);
            #pragma unroll
            for (int j = 0; j < 8; ++j) {
                ushort2 pk;
                pk.x = ((const unsigned short*)&vr0)[j];
                pk.y = ((const unsigned short*)&vr1)[j];
                *reinterpret_cast<ushort2*>(&vTw[(g*8 + j)*40 + c*2]) = pk;
            }
        }
        #pragma unroll
        for (int mt = 0; mt < 2; ++mt) {
            int posA = p0 + mt*16 + c;
            bf16x8 af = *reinterpret_cast<const bf16x8*>(&kb[((size_t)(b*NN + posA))*128 + h*32 + g*8]);
            f32x4 z4 = {0.f,0.f,0.f,0.f};
            f32x4 y0 = __builtin_amdgcn_mfma_f32_16x16x32_bf16(af, wb[0], z4, 0, 0, 0);
            f32x4 y1 = __builtin_amdgcn_mfma_f32_16x16x32_bf16(af, wb[1], z4, 0, 0, 0);
            f32x4 el0, eh0, el1, eh1;
            #pragma unroll
            for (int r = 0; r < 4; ++r) {
                float a0 = 2.f*(y0[r] + bias0);
                float a1 = 2.f*(y1[r] + bias1);
                el0[r] = __expf(a0); eh0[r] = __expf(-a0);
                el1[r] = __expf(a1); eh1[r] = __expf(-a1);
            }
            f32x4 s = el0 + eh0 + el1 + eh1;
            red16(s);
            f32x4 rs;
            #pragma unroll
            for (int r = 0; r < 4; ++r) rs[r] = rcpf(s[r]);
            f32x4 klo0 = el0*rs, khi0 = eh0*rs, klo1 = el1*rs, khi1 = eh1*rs;
            km0 += klo0; km1 += khi0; km2 += klo1; km3 += khi1;
            int posC = p0 + mt*16 + g*4;
            ushort4 wlo0, whi0, wlo1, whi1;
            #pragma unroll
            for (int r = 0; r < 4; ++r) {
                unsigned int u = fsc[((size_t)h*NN + posC + r)*16 + c];
                float fsv = bf2f((unsigned short)(u & 0xffffu));
                float fcv = bf2f((unsigned short)(u >> 16));
                ((unsigned short*)&wlo0)[r] = f2bf(klo0[r]*fcv + khi0[r]*fsv);
                ((unsigned short*)&whi0)[r] = f2bf(khi0[r]*fcv - klo0[r]*fsv);
                ((unsigned short*)&wlo1)[r] = f2bf(klo1[r] + khi1[r]);
                ((unsigned short*)&whi1)[r] = f2bf(khi1[r] - klo1[r]);
            }
            int po = mt*16 + g*4;
            *reinterpret_cast<ushort4*>(&kfsTw[(c)*40 + po])      = wlo0;
            *reinterpret_cast<ushort4*>(&kfsTw[(32 + c)*40 + po]) = whi0;
            *reinterpret_cast<ushort4*>(&kfsTw[(16 + c)*40 + po]) = wlo1;
            *reinterpret_cast<ushort4*>(&kfsTw[(48 + c)*40 + po]) = whi1;
        }
        {
            bf16x8 bf0 = *reinterpret_cast<const bf16x8*>(&vTw[(c)*40 + g*8]);
            bf16x8 bf1 = *reinterpret_cast<const bf16x8*>(&vTw[(16 + c)*40 + g*8]);
            #pragma unroll
            for (int mt = 0; mt < 4; ++mt) {
                bf16x8 af2 = *reinterpret_cast<const bf16x8*>(&kfsTw[(mt*16 + c)*40 + g*8]);
                acc[mt][0] = __builtin_amdgcn_mfma_f32_16x16x32_bf16(af2, bf0, acc[mt][0], 0, 0, 0);
                acc[mt][1] = __builtin_amdgcn_mfma_f32_16x16x32_bf16(af2, bf1, acc[mt][1], 0, 0, 0);
            }
        }
    }
    float kv0 = km0[0]+km0[1]+km0[2]+km0[3];
    float kv1 = km1[0]+km1[1]+km1[2]+km1[3];
    float kv2 = km2[0]+km2[1]+km2[2]+km2[3];
    float kv3 = km3[0]+km3[1]+km3[2]+km3[3];
    kv0 += __shfl_xor(kv0, 16); kv0 += __shfl_xor(kv0, 32);
    kv1 += __shfl_xor(kv1, 16); kv1 += __shfl_xor(kv1, 32);
    kv2 += __shfl_xor(kv2, 16); kv2 += __shfl_xor(kv2, 32);
    kv3 += __shfl_xor(kv3, 16); kv3 += __shfl_xor(kv3, 32);
    if (g == 0) {
        kms[w][c] = kv0; kms[w][16 + c] = kv2; kms[w][32 + c] = kv1; kms[w][48 + c] = kv3;
    }
    __syncthreads();
    float* kvred = reinterpret_cast<float*>(smem);
    #pragma unroll
    for (int mt = 0; mt < 4; ++mt)
        #pragma unroll
        for (int nt = 0; nt < 2; ++nt) {
            int d = nt*16 + c;
            *reinterpret_cast<f32x4*>(&kvred[(size_t)(w*32 + d)*68 + mt*16 + g*4]) = acc[mt][nt];
        }
    __syncthreads();
    #pragma unroll
    for (int i = 0; i < 8; ++i) {
        int idx = t*8 + i;
        int f = idx >> 5, d = idx & 31;
        float s2 = kvred[(0*32 + d)*68 + f] + kvred[(1*32 + d)*68 + f]
                 + kvred[(2*32 + d)*68 + f] + kvred[(3*32 + d)*68 + f];
        kvpart[((size_t)(bh*32 + chunk))*2048 + idx] = s2;
    }
    if (t < 64) {
        float s2 = kms[0][t] + kms[1][t] + kms[2][t] + kms[3][t];
        kmpart[(size_t)(bh*32 + chunk)*64 + t] = s2;
    }
}

// ---------------------------------------------------------------- reduce kv partials -> kvT bf16 [bh][d][f]; + kmean
__global__ __launch_bounds__(256) void k_kvred2(const float* __restrict__ kvpart, const float* __restrict__ kmpart,
                                                unsigned short* __restrict__ kvT, float* __restrict__ kmean)
{
    int bh = blockIdx.x >> 3, part = blockIdx.x & 7;
    int idx = part*256 + threadIdx.x;
    float s = 0.f;
    for (int cidx = 0; cidx < 32; ++cidx) s += kvpart[((size_t)(bh*32 + cidx))*2048 + idx];
    int f = idx >> 5, d = idx & 31;
    kvT[(size_t)bh*2048 + d*64 + f] = f2bf(s * (1.f/16384.f));
    if (part == 0 && threadIdx.x < 64) {
        int tt = threadIdx.x;
        float sm = 0.f;
        for (int cidx = 0; cidx < 32; ++cidx) sm += kmpart[(size_t)(bh*32 + cidx)*64 + tt];
        kmean[bh*64 + tt] = sm * (1.f/16384.f);
    }
}

// ---------------------------------------------------------------- fused q-features (MFMA) + xs (MFMA) -> xsb bf16
__global__ __launch_bounds__(256) void k_featxs(
    const unsigned short* __restrict__ qb, const float* __restrict__ W, const float* __restrict__ bvec,
    const unsigned int* __restrict__ fsc, const unsigned short* __restrict__ kvT,
    const float* __restrict__ kmean, const unsigned short* __restrict__ xspb, unsigned short* __restrict__ xsb)
{
    __shared__ __align__(16) unsigned short qfs[4][32][72];
    int bh = blockIdx.y, b = bh >> 2, h = bh & 3;
    int chunk = blockIdx.x;
    int t = threadIdx.x, w = t >> 6, lane = t & 63;
    int c = lane & 15, g = lane >> 4;
    bf16x8 wb[2];
    #pragma unroll
    for (int et = 0; et < 2; ++et) {
        float4 wa = *reinterpret_cast<const float4*>(&W[(c + et*16)*32 + g*8]);
        float4 wb2 = *reinterpret_cast<const float4*>(&W[(c + et*16)*32 + g*8 + 4]);
        wb[et] = cvt8(wa, wb2);
    }
    float bias0 = bvec[c], bias1 = bvec[c + 16];
    float kml0 = kmean[bh*64 + c],      kml1 = kmean[bh*64 + 16 + c];
    float kmh0 = kmean[bh*64 + 32 + c], kmh1 = kmean[bh*64 + 48 + c];
    bf16x8 bkv[2][2];
    #pragma unroll
    for (int nt = 0; nt < 2; ++nt)
        #pragma unroll
        for (int ks = 0; ks < 2; ++ks)
            bkv[nt][ks] = *reinterpret_cast<const bf16x8*>(&kvT[(size_t)bh*2048 + (nt*16 + c)*64 + ks*32 + g*8]);

    for (int rnd = 0; rnd < 4; ++rnd) {
        int p0 = chunk*512 + w*128 + rnd*32;
        #pragma unroll
        for (int mt = 0; mt < 2; ++mt) {
            int posA = p0 + mt*16 + c;
            bf16x8 af = *reinterpret_cast<const bf16x8*>(&qb[((size_t)(b*NN + posA))*128 + h*32 + g*8]);
            f32x4 z4 = {0.f,0.f,0.f,0.f};
            f32x4 y0 = __builtin_amdgcn_mfma_f32_16x16x32_bf16(af, wb[0], z4, 0, 0, 0);
            f32x4 y1 = __builtin_amdgcn_mfma_f32_16x16x32_bf16(af, wb[1], z4, 0, 0, 0);
            f32x4 el0, eh0, el1, eh1;
            #pragma unroll
            for (int r = 0; r < 4; ++r) {
                float a0 = 2.f*(y0[r] + bias0);
                float a1 = 2.f*(y1[r] + bias1);
                el0[r] = __expf(a0); eh0[r] = __expf(-a0);
                el1[r] = __expf(a1); eh1[r] = __expf(-a1);
            }
            f32x4 s = el0 + eh0 + el1 + eh1;
            f32x4 wv = el0*kml0 + eh0*kmh0 + el1*kml1 + eh1*kmh1;
            red16x2(s, wv);
            f32x4 zr;
            #pragma unroll
            for (int r = 0; r < 4; ++r) {
                float rs = rcpf(s[r]);
                float z = rcpf(wv[r]*rs + 1e-6f);
                zr[r] = z*rs;
            }
            int posC = mt*16 + g*4;
            #pragma unroll
            for (int r = 0; r < 4; ++r) {
                unsigned int u = fsc[((size_t)h*NN + p0 + posC + r)*16 + c];
                float fsv = bf2f((unsigned short)(u & 0xffffu));
                float fcv = bf2f((unsigned short)(u >> 16));
                qfs[w][posC + r][c]      = f2bf(zr[r]*(el0[r]*fcv + eh0[r]*fsv));
                qfs[w][posC + r][32 + c] = f2bf(zr[r]*(eh0[r]*fcv - el0[r]*fsv));
                qfs[w][posC + r][16 + c] = f2bf(zr[r]*(el1[r] + eh1[r]));
                qfs[w][posC + r][48 + c] = f2bf(zr[r]*(eh1[r] - el1[r]));
            }
        }
        f32x4 acc[2][2];
        #pragma unroll
        for (int i = 0; i < 2; ++i) { acc[i][0] = (f32x4){0.f,0.f,0.f,0.f}; acc[i][1] = (f32x4){0.f,0.f,0.f,0.f}; }
        #pragma unroll
        for (int ks = 0; ks < 2; ++ks)
            #pragma unroll
            for (int mt = 0; mt < 2; ++mt) {
                bf16x8 af2 = *reinterpret_cast<const bf16x8*>(&qfs[w][mt*16 + c][ks*32 + g*8]);
                acc[mt][0] = __builtin_amdgcn_mfma_f32_16x16x32_bf16(af2, bkv[0][ks], acc[mt][0], 0, 0, 0);
                acc[mt][1] = __builtin_amdgcn_mfma_f32_16x16x32_bf16(af2, bkv[1][ks], acc[mt][1], 0, 0, 0);
            }
        #pragma unroll
        for (int mt = 0; mt < 2; ++mt)
            #pragma unroll
            for (int nt = 0; nt < 2; ++nt) {
                int d = nt*16 + c;
                #pragma unroll
                for (int r = 0; r < 4; ++r) {
                    int pos = p0 + mt*16 + g*4 + r;
                    size_t off = ((size_t)(b*NN + pos))*128 + h*32 + d;
                    xsb[off] = f2bf(bf2f(xspb[off]) + acc[mt][nt][r]);
                }
            }
    }
}

// ---------------------------------------------------------------- gram via MFMA + fused norms
__global__ __launch_bounds__(256) void k_gram(const unsigned short* __restrict__ qb, const unsigned short* __restrict__ kb,
                                              float* __restrict__ Gpart,
                                              float* __restrict__ qn2, float* __restrict__ kn2)
{
    __shared__ unsigned short qTs[128][40];
    __shared__ unsigned short kTs[128][40];
    int kc = blockIdx.x, bb = blockIdx.y;
    int t = threadIdx.x, lane = t & 63;
    int wave = t >> 6, wm = wave >> 1, wn = wave & 1;
    int c = t & 127, lh = t >> 7;
    float qa = 0.f, ka = 0.f;
    f32x4 acc[4][4];
    #pragma unroll
    for (int i = 0; i < 4; ++i)
        #pragma unroll
        for (int j = 0; j < 4; ++j) acc[i][j] = (f32x4){0.f,0.f,0.f,0.f};

    for (int kt = 0; kt < 8; ++kt) {
        __syncthreads();
        #pragma unroll
        for (int i = 0; i < 16; ++i) {
            int l = lh*16 + i;
            size_t pos = (size_t)bb*NN + kc*256 + kt*32 + l;
            unsigned short qu = qb[pos*128 + c];
            unsigned short ku = kb[pos*128 + c];
            float qv = bf2f(qu), kvv = bf2f(ku);
            qa += qv*qv; ka += kvv*kvv;
            qTs[c][l] = qu;
            kTs[c][l] = ku;
        }
        __syncthreads();
        bf16x8 af[4];
        #pragma unroll
        for (int mi = 0; mi < 4; ++mi)
            af[mi] = *reinterpret_cast<const bf16x8*>(&qTs[wm*64 + mi*16 + (lane & 15)][(lane >> 4)*8]);
        #pragma unroll
        for (int ni = 0; ni < 4; ++ni) {
            bf16x8 bfr = *reinterpret_cast<const bf16x8*>(&kTs[wn*64 + ni*16 + (lane & 15)][(lane >> 4)*8]);
            #pragma unroll
            for (int mi = 0; mi < 4; ++mi)
                acc[mi][ni] = __builtin_amdgcn_mfma_f32_16x16x32_bf16(af[mi], bfr, acc[mi][ni], 0, 0, 0);
        }
    }
    size_t gb = ((size_t)(bb*64 + kc))*16384;
    #pragma unroll
    for (int mi = 0; mi < 4; ++mi) {
        #pragma unroll
        for (int ni = 0; ni < 4; ++ni) {
            int d = wn*64 + ni*16 + (lane & 15);
            #pragma unroll
            for (int r = 0; r < 4; ++r) {
                int cc = wm*64 + mi*16 + (lane >> 4)*4 + r;
                Gpart[gb + (size_t)cc*128 + d] = acc[mi][ni][r];
            }
        }
    }
    atomicAdd(&qn2[bb*128 + c], qa);
    atomicAdd(&kn2[bb*128 + c], ka);
}

// ---------------------------------------------------------------- channel attention softmax (fused Gpart reduction)
__global__ __launch_bounds__(128) void k_attnsm(const float* __restrict__ Gpart, const float* __restrict__ qn2,
    const float* __restrict__ kn2, const float* __restrict__ temp, float* __restrict__ attn)
{
    __shared__ float red[128];
    int row = blockIdx.x;
    int b = row >> 7, c = row & 127;
    int t = threadIdx.x;
    float s0 = 0.f;
    for (int kc = 0; kc < 64; ++kc)
        s0 += Gpart[((size_t)(b*64 + kc))*16384 + (size_t)c*128 + t];
    float qn = fmaxf(sqrtf(qn2[b*128 + c]), 1e-12f);
    float kn = fmaxf(sqrtf(kn2[b*128 + t]), 1e-12f);
    float val = s0 / (qn*kn) * temp[c];
    red[t] = val; __syncthreads();
    for (int s = 64; s > 0; s >>= 1) { if (t < s) red[t] = fmaxf(red[t], red[t+s]); __syncthreads(); }
    float mm = red[0]; __syncthreads();
    float ev = expf(val - mm);
    red[t] = ev; __syncthreads();
    for (int s = 64; s > 0; s >>= 1) { if (t < s) red[t] += red[t+s]; __syncthreads(); }
    attn[(size_t)row*128 + t] = ev / red[0];
}

// ---------------------------------------------------------------- per-batch B matrix, transposed bf16
__global__ __launch_bounds__(256) void k_bmat(const float* __restrict__ attn, const float* __restrict__ Wp,
                                              unsigned short* __restrict__ BmatT)
{
    int b = blockIdx.y, kk = blockIdx.x, o = threadIdx.x;
    float val;
    if (kk < 128) {
        val = Wp[(size_t)o*256 + kk];
    } else {
        int d = kk - 128;
        __shared__ float a[128];
        if (o < 128) a[o] = attn[((size_t)b*128 + o)*128 + d];
        __syncthreads();
        float acc = 0.f;
        for (int c = 0; c < 128; ++c) acc += a[c] * Wp[(size_t)o*256 + 128 + c];
        val = acc;
    }
    BmatT[((size_t)b*256 + o)*256 + kk] = f2bf(val);
}

// ---------------------------------------------------------------- final MFMA GEMM with T14 prefetch (direct-store epilogue)
__global__ __launch_bounds__(256) void k_out_mfma(const unsigned short* __restrict__ xsb,
    const unsigned short* __restrict__ vb, const unsigned short* __restrict__ BmatT,
    const float* __restrict__ bp, float* __restrict__ out)
{
    __shared__ unsigned short Asm[128*64];
    __shared__ unsigned short Bsm[128*64];
    int t = threadIdx.x;
    int lin = blockIdx.y*2 + blockIdx.x;
    int logical = (lin & 7)*256 + (lin >> 3);
    int ntile = logical & 1;
    int mtile = logical >> 1;
    int m0 = mtile * 128;
    int n0 = ntile * 128;
    int b = mtile >> 7;
    int wave = t >> 6, lane = t & 63;
    int wm = wave >> 1, wn = wave & 1;
    int lrow = lane & 15, lk = lane >> 4;
    f32x4 acc[4][4];
    #pragma unroll
    for (int i = 0; i < 4; ++i)
        #pragma unroll
        for (int j = 0; j < 4; ++j) acc[i][j] = (f32x4){0.f,0.f,0.f,0.f};

    int am = t >> 3, ak8 = t & 7;
    uint4 pa4[4];
    #pragma unroll
    for (int p = 0; p < 4; ++p)
        pa4[p] = *reinterpret_cast<const uint4*>(&xsb[(size_t)(m0 + am + p*32)*128 + ak8*8]);

    #pragma unroll
    for (int kt = 0; kt < 4; ++kt) {
        if (kt) __syncthreads();
        #pragma unroll
        for (int p = 0; p < 4; ++p) {
            int m = am + p*32;
            int byte = m*128 + ((ak8 ^ (m & 7)) << 4);
            *reinterpret_cast<uint4*>(reinterpret_cast<char*>(Asm) + byte) = pa4[p];
        }
        {
            int n = t >> 3, k8 = t & 7;
            #pragma unroll
            for (int p = 0; p < 4; ++p, n += 32) {
                uint4 u4 = *reinterpret_cast<const uint4*>(&BmatT[((size_t)b*256 + n0 + n)*256 + kt*64 + k8*8]);
                int byte = n*128 + ((k8 ^ (n & 7)) << 4);
                *reinterpret_cast<uint4*>(reinterpret_cast<char*>(Bsm) + byte) = u4;
            }
        }
        if (kt < 3) {
            const unsigned short* Asrc = ((kt+1) < 2) ? xsb : vb;
            int ka0 = ((kt+1) & 1) * 64;
            #pragma unroll
            for (int p = 0; p < 4; ++p)
                pa4[p] = *reinterpret_cast<const uint4*>(&Asrc[(size_t)(m0 + am + p*32)*128 + ka0 + ak8*8]);
        }
        __syncthreads();
        #pragma unroll
        for (int ks = 0; ks < 2; ++ks) {
            bf16x8 af[4], bfv[4];
            #pragma unroll
            for (int mi = 0; mi < 4; ++mi) {
                int m = wm*64 + mi*16 + lrow;
                int u = (ks*4 + lk) ^ (m & 7);
                af[mi] = *reinterpret_cast<const bf16x8*>(reinterpret_cast<const char*>(Asm) + m*128 + u*16);
            }
            #pragma unroll
            for (int ni = 0; ni < 4; ++ni) {
                int n = wn*64 + ni*16 + lrow;
                int u = (ks*4 + lk) ^ (n & 7);
                bfv[ni] = *reinterpret_cast<const bf16x8*>(reinterpret_cast<const char*>(Bsm) + n*128 + u*16);
            }
            #pragma unroll
            for (int mi = 0; mi < 4; ++mi)
                #pragma unroll
                for (int ni = 0; ni < 4; ++ni)
                    acc[mi][ni] = __builtin_amdgcn_mfma_f32_16x16x32_bf16(af[mi], bfv[ni], acc[mi][ni], 0, 0, 0);
        }
    }
    #pragma unroll
    for (int mi = 0; mi < 4; ++mi) {
        #pragma unroll
        for (int ni = 0; ni < 4; ++ni) {
            int gcol = n0 + wn*64 + ni*16 + lrow;
            float bias = bp[gcol];
            #pragma unroll
            for (int r = 0; r < 4; ++r) {
                size_t grow = (size_t)m0 + wm*64 + mi*16 + lk*4 + r;
                out[grow*256 + gcol] = acc[mi][ni][r] + bias;
            }
        }
    }
}

extern "C" void kernel_launch(void* const* d_in, const int* in_sizes, int n_in,
                              void* d_out, int out_size, void* d_ws, size_t ws_size,
                              hipStream_t stream)
{
    (void)in_sizes; (void)n_in; (void)out_size; (void)ws_size;
    const float* x    = (const float*)d_in[0];
    const float* Wq   = (const float*)d_in[1];
    const float* bq   = (const float*)d_in[2];
    const float* Wk   = (const float*)d_in[3];
    const float* bk   = (const float*)d_in[4];
    const float* Wv   = (const float*)d_in[5];
    const float* bv   = (const float*)d_in[6];
    const float* Whq  = (const float*)d_in[7];
    const float* bhq  = (const float*)d_in[8];
    const float* Whk  = (const float*)d_in[9];
    const float* bhk  = (const float*)d_in[10];
    const float* sinc = (const float*)d_in[11];
    const float* cosc = (const float*)d_in[12];
    const float* lw   = (const float*)d_in[13];
    const float* lb   = (const float*)d_in[14];
    const float* temp = (const float*)d_in[15];
    const float* Wp   = (const float*)d_in[16];
    const float* bp   = (const float*)d_in[17];

    float* out = (float*)d_out;
    float* q   = out + 33554432;
    float* k   = out + 50331648;
    float* ws  = (float*)d_ws;

    unsigned short* xspb = (unsigned short*)(ws + WS_XSPB);
    float* Gpart  = ws + WS_GPART;
    unsigned short* vbuf = (unsigned short*)(ws + WS_VB);
    unsigned short* xsb  = (unsigned short*)(ws + WS_XSB);
    unsigned int* fsc = (unsigned int*)(ws + WS_FS);
    float* inv    = ws + WS_INV;
    float* cs     = ws + WS_CS;
    float* cc     = ws + WS_CC;
    unsigned short* Wc = (unsigned short*)(ws + WS_WCAT);
    float* bcat   = ws + WS_BCAT;
    float* kvpart = ws + WS_KVPART;
    float* kmpart = ws + WS_KMPART;
    unsigned short* kvT = (unsigned short*)(ws + WS_KV);
    float* kmean  = ws + WS_KMEAN;
    float* qn2    = ws + WS_QN2;
    float* kn2    = ws + WS_KN2;
    float* attn   = ws + WS_ATTN;
    unsigned short* BmatT = (unsigned short*)(ws + WS_BMATT);
    unsigned short* qbuf  = (unsigned short*)(ws + WS_QB);
    unsigned short* kbuf  = (unsigned short*)(ws + WS_KB);

    hipMemsetAsync(qn2, 0, 2048*sizeof(float), stream);

    k_wprep<<<385, 256, 0, stream>>>(Wq, Wk, Wv, bq, bk, bv, sinc, cosc, Wc, bcat, inv, cs, cc);
    k_tables<<<4096, 256, 0, stream>>>(inv, cs, cc, fsc);
    k_qkv_mfma<<<1024, 512, 0, stream>>>(x, Wc, bcat, q, k, qbuf, kbuf, vbuf);
    k_conv<<<dim3(8, 128, 8), 256, 0, stream>>>(vbuf, lw, lb, xspb);
    k_featkv<<<dim3(32, 32), 256, 0, stream>>>(kbuf, vbuf, Whk, bhk, fsc, kvpart, kmpart);
    k_kvred2<<<256, 256, 0, stream>>>(kvpart, kmpart, kvT, kmean);
    k_featxs<<<dim3(32, 32), 256, 0, stream>>>(qbuf, Whq, bhq, fsc, kvT, kmean, xspb, xsb);
    k_gram<<<dim3(64, 8), 256, 0, stream>>>(qbuf, kbuf, Gpart, qn2, kn2);
    k_attnsm<<<1024, 128, 0, stream>>>(Gpart, qn2, kn2, temp, attn);
    k_bmat<<<dim3(256, 8), 256, 0, stream>>>(attn, Wp, BmatT);
    k_out_mfma<<<dim3(2, 1024), 256, 0, stream>>>(xsb, vbuf, BmatT, bp, out);
}

// Round 13
// 355.856 us; speedup vs baseline: 1.3205x; 1.0326x over previous
//
#include <hip/hip_runtime.h>
#include <cmath>

#define NB 8
#define NN 16384
#define DIN 23
#define DOUT 16

typedef short bf16x8 __attribute__((ext_vector_type(8)));
typedef float f32x4 __attribute__((ext_vector_type(4)));

__device__ __forceinline__ unsigned short f2bf(float f) {
    unsigned int u = __float_as_uint(f);
    u += 0x7FFFu + ((u >> 16) & 1u);
    return (unsigned short)(u >> 16);
}
__device__ __forceinline__ float bf2f(unsigned short s) {
    return __uint_as_float(((unsigned int)s) << 16);
}
__device__ __forceinline__ float rcpf(float x) { return __builtin_amdgcn_rcpf(x); }

__device__ __forceinline__ bf16x8 cvt8(float4 a, float4 b) {
    bf16x8 r;
    r[0]=(short)f2bf(a.x); r[1]=(short)f2bf(a.y); r[2]=(short)f2bf(a.z); r[3]=(short)f2bf(a.w);
    r[4]=(short)f2bf(b.x); r[5]=(short)f2bf(b.y); r[6]=(short)f2bf(b.z); r[7]=(short)f2bf(b.w);
    return r;
}
__device__ __forceinline__ void red16(f32x4& s) {
    #pragma unroll
    for (int off = 1; off < 16; off <<= 1) {
        s[0] += __shfl_xor(s[0], off); s[1] += __shfl_xor(s[1], off);
        s[2] += __shfl_xor(s[2], off); s[3] += __shfl_xor(s[3], off);
    }
}
__device__ __forceinline__ void red16x2(f32x4& s, f32x4& w) {
    #pragma unroll
    for (int off = 1; off < 16; off <<= 1) {
        s[0] += __shfl_xor(s[0], off); s[1] += __shfl_xor(s[1], off);
        s[2] += __shfl_xor(s[2], off); s[3] += __shfl_xor(s[3], off);
        w[0] += __shfl_xor(w[0], off); w[1] += __shfl_xor(w[1], off);
        w[2] += __shfl_xor(w[2], off); w[3] += __shfl_xor(w[3], off);
    }
}

// workspace offsets in floats
#define WS_XSPB   ((size_t)0)
#define WS_G      ((size_t)8388608)    // G f32: 131,072 (atomic target)
#define WS_VB     ((size_t)16777216)
#define WS_XSB    ((size_t)25165824)
#define WS_FS     ((size_t)33554432)
#define WS_INV    ((size_t)35651584)
#define WS_CS     ((size_t)35651648)
#define WS_CC     ((size_t)35653184)
#define WS_WCAT   ((size_t)35654720)
#define WS_BCAT   ((size_t)35703872)
#define WS_KVPART ((size_t)35704256)
#define WS_KMPART ((size_t)37801408)
#define WS_KV     ((size_t)37866944)
#define WS_KMEAN  ((size_t)37932480)
#define WS_QN2    ((size_t)37934528)
#define WS_KN2    ((size_t)37935552)
#define WS_ATTN   ((size_t)38067648)
#define WS_BMATT  ((size_t)38198720)
#define WS_QB     ((size_t)38460864)
#define WS_KB     ((size_t)46849472)

// ---------------------------------------------------------------- weights prep + setup (merged)
__global__ __launch_bounds__(256) void k_wprep(
    const float* __restrict__ Wq, const float* __restrict__ Wk, const float* __restrict__ Wv,
    const float* __restrict__ bq, const float* __restrict__ bk, const float* __restrict__ bv,
    const float* __restrict__ sc, const float* __restrict__ ccin,
    unsigned short* __restrict__ Wc, float* __restrict__ bcat,
    float* __restrict__ inv, float* __restrict__ cs, float* __restrict__ cc)
{
    int row = blockIdx.x, t = threadIdx.x;
    if (row == 384) {
        if (t >= 64) return;
        if (t < DIN) inv[t] = (float)pow(10000.0, -((double)(2 * t)) / 64.0);
        int h = t >> 4, d = t & 15;
        float ss = 0.f, s2 = 0.f;
        for (int D = 0; D < DIN; ++D) { ss += sc[(h*DIN + D)*DOUT + d]; s2 += ccin[(h*DIN + D)*DOUT + d]; }
        float rs = 1.f / ss, r2 = 1.f / s2;
        for (int D = 0; D < DIN; ++D) {
            cs[(h*DIN + D)*DOUT + d] = sc[(h*DIN + D)*DOUT + d] * rs;
            cc[(h*DIN + D)*DOUT + d] = ccin[(h*DIN + D)*DOUT + d] * r2;
        }
        return;
    }
    const float* W = (row < 128) ? Wq : (row < 256) ? Wk : Wv;
    const float* bb = (row < 128) ? bq : (row < 256) ? bk : bv;
    int r = row & 127;
    Wc[(size_t)row*256 + t] = f2bf(W[(size_t)r*256 + t]);
    if (t == 0) bcat[row] = bb[r];
}

// ---------------------------------------------------------------- FoPE table fsc
__global__ __launch_bounds__(256) void k_tables(const float* __restrict__ inv, const float* __restrict__ cs,
                                                const float* __restrict__ cc,
                                                unsigned int* __restrict__ fsc)
{
    int t = threadIdx.x;
    int sub = t >> 6, lane = t & 63;
    int tpos = blockIdx.x*4 + sub;
    __shared__ float ssin[4][DIN], scos[4][DIN];
    if (lane < DIN) { float fr = (float)tpos * inv[lane]; ssin[sub][lane] = sinf(fr); scos[sub][lane] = cosf(fr); }
    __syncthreads();
    int h = lane >> 4, d = lane & 15;
    float as = 0.f, ac = 0.f;
    for (int D = 0; D < DIN; ++D) { as += ssin[sub][D]*cs[(h*DIN + D)*DOUT + d]; ac += scos[sub][D]*cc[(h*DIN + D)*DOUT + d]; }
    fsc[((size_t)h*NN + tpos)*16 + d] = ((unsigned int)f2bf(ac) << 16) | (unsigned int)f2bf(as);
}

// ---------------------------------------------------------------- QKV MFMA GEMM: BM=128 x BN=384 (q|k|v fused), 8 waves
__global__ __launch_bounds__(512) void k_qkv_mfma(const float* __restrict__ x,
    const unsigned short* __restrict__ Wc, const float* __restrict__ bcat,
    float* __restrict__ q, float* __restrict__ k,
    unsigned short* __restrict__ qb, unsigned short* __restrict__ kb,
    unsigned short* __restrict__ vb)
{
    __shared__ __align__(16) char smem[65536];   // A: [0,16K) bf16 128x64 swz; B: [16K,64K) bf16 384x64 swz
    int t = threadIdx.x;
    int lin = blockIdx.x;
    int mtile = (lin & 7)*128 + (lin >> 3);      // bijective XCD swizzle (1024 % 8 == 0)
    int m0 = mtile * 128;
    int wave = t >> 6, lane = t & 63;
    int wm = wave >> 2, wn = wave & 3;           // 2M x 4N
    int lrow = lane & 15, lk = lane >> 4;
    f32x4 acc[4][6];
    #pragma unroll
    for (int i = 0; i < 4; ++i)
        #pragma unroll
        for (int j = 0; j < 6; ++j) acc[i][j] = (f32x4){0.f,0.f,0.f,0.f};

    int am = t >> 4, ak4 = t & 15;
    size_t arow = (size_t)(m0 + am);
    float4 pa[4];
    #pragma unroll
    for (int p = 0; p < 4; ++p)
        pa[p] = *reinterpret_cast<const float4*>(&x[(arow + p*32)*256 + ak4*4]);

    #pragma unroll
    for (int kt = 0; kt < 4; ++kt) {
        int k0 = kt * 64;
        if (kt) __syncthreads();
        #pragma unroll
        for (int p = 0; p < 4; ++p) {
            int m = am + p*32;
            ushort4 b4;
            b4.x = f2bf(pa[p].x); b4.y = f2bf(pa[p].y); b4.z = f2bf(pa[p].z); b4.w = f2bf(pa[p].w);
            int byte = m*128 + ((ak4*8) ^ ((m & 7) << 4));
            *reinterpret_cast<ushort4*>(smem + byte) = b4;
        }
        {
            int n = t >> 3, k8 = t & 7;
            #pragma unroll
            for (int p = 0; p < 6; ++p, n += 64) {
                uint4 u4 = *reinterpret_cast<const uint4*>(&Wc[(size_t)n*256 + k0 + k8*8]);
                int byte = n*128 + ((k8 ^ (n & 7)) << 4);
                *reinterpret_cast<uint4*>(smem + 16384 + byte) = u4;
            }
        }
        if (kt < 3) {
            #pragma unroll
            for (int p = 0; p < 4; ++p)
                pa[p] = *reinterpret_cast<const float4*>(&x[(arow + p*32)*256 + (kt+1)*64 + ak4*4]);
        }
        __syncthreads();
        #pragma unroll
        for (int ks = 0; ks < 2; ++ks) {
            bf16x8 af[4];
            #pragma unroll
            for (int mi = 0; mi < 4; ++mi) {
                int m = wm*64 + mi*16 + lrow;
                int u = (ks*4 + lk) ^ (m & 7);
                af[mi] = *reinterpret_cast<const bf16x8*>(smem + m*128 + u*16);
            }
            #pragma unroll
            for (int ni = 0; ni < 6; ++ni) {
                int n = wn*96 + ni*16 + lrow;
                int u = (ks*4 + lk) ^ (n & 7);
                bf16x8 bfv = *reinterpret_cast<const bf16x8*>(smem + 16384 + n*128 + u*16);
                #pragma unroll
                for (int mi = 0; mi < 4; ++mi)
                    acc[mi][ni] = __builtin_amdgcn_mfma_f32_16x16x32_bf16(af[mi], bfv, acc[mi][ni], 0, 0, 0);
            }
        }
    }
    // epilogue: direct stores; q/k f32 are pure outputs -> nontemporal
    #pragma unroll
    for (int mi = 0; mi < 4; ++mi) {
        #pragma unroll
        for (int ni = 0; ni < 6; ++ni) {
            int gcol = wn*96 + ni*16 + lrow;
            int c = gcol & 127;
            float bias = bcat[gcol];
            #pragma unroll
            for (int r = 0; r < 4; ++r) {
                size_t grow = (size_t)m0 + wm*64 + mi*16 + lk*4 + r;
                float val = acc[mi][ni][r] + bias;
                if (gcol < 128)      { __builtin_nontemporal_store(val, &q[grow*128 + c]); qb[grow*128 + c] = f2bf(val); }
                else if (gcol < 256) { __builtin_nontemporal_store(val, &k[grow*128 + c]); kb[grow*128 + c] = f2bf(val); }
                else                 vb[grow*128 + c] = f2bf(val);
            }
        }
    }
}

// ---------------------------------------------------------------- depthwise 3x3 LEPE conv, 8 ch/lane -> xspb bf16
__global__ __launch_bounds__(256) void k_conv(const unsigned short* __restrict__ vb, const float* __restrict__ w,
                                              const float* __restrict__ bias, unsigned short* __restrict__ xspb)
{
    __shared__ float wsmT[9][128];
    __shared__ float bsm[128];
    int t = threadIdx.x;
    for (int i = t; i < 1152; i += 256) wsmT[i % 9][i / 9] = w[i];
    if (t < 128) bsm[t] = bias[t];
    __syncthreads();
    int jj = t >> 4, c8 = (t & 15) * 8;
    int j = blockIdx.x * 16 + jj;
    int i = blockIdx.y, b = blockIdx.z;
    float acc[8];
    #pragma unroll
    for (int l = 0; l < 8; ++l) acc[l] = bsm[c8 + l];
    #pragma unroll
    for (int di = 0; di < 3; ++di) {
        int ii = i + di - 1;
        if (ii < 0 || ii >= 128) continue;
        #pragma unroll
        for (int dj = 0; dj < 3; ++dj) {
            int jx = j + dj - 1;
            if (jx < 0 || jx >= 128) continue;
            uint4 u = *reinterpret_cast<const uint4*>(&vb[((size_t)b*NN + ii*128 + jx)*128 + c8]);
            const unsigned short* us = (const unsigned short*)&u;
            int kk = di*3 + dj;
            #pragma unroll
            for (int l = 0; l < 8; ++l)
                acc[l] += wsmT[kk][c8 + l] * bf2f(us[l]);
        }
    }
    ushort4 r0, r1;
    r0.x = f2bf(acc[0]); r0.y = f2bf(acc[1]); r0.z = f2bf(acc[2]); r0.w = f2bf(acc[3]);
    r1.x = f2bf(acc[4]); r1.y = f2bf(acc[5]); r1.z = f2bf(acc[6]); r1.w = f2bf(acc[7]);
    size_t ob = ((size_t)b*NN + i*128 + j)*128 + c8;
    *reinterpret_cast<ushort4*>(&xspb[ob]) = r0;
    *reinterpret_cast<ushort4*>(&xspb[ob+4]) = r1;
}

// ---------------------------------------------------------------- fused k-features (MFMA) + kv partials (MFMA)
__global__ __launch_bounds__(256) void k_featkv(
    const unsigned short* __restrict__ kb, const unsigned short* __restrict__ vb,
    const float* __restrict__ W, const float* __restrict__ bvec,
    const unsigned int* __restrict__ fsc,
    float* __restrict__ kvpart, float* __restrict__ kmpart)
{
    __shared__ __align__(16) char smem[34816];
    __shared__ float kms[4][64];
    int bh = blockIdx.y, b = bh >> 2, h = bh & 3;
    int chunk = blockIdx.x;
    int t = threadIdx.x, w = t >> 6, lane = t & 63;
    int c = lane & 15, g = lane >> 4;
    unsigned short* kfsTw = reinterpret_cast<unsigned short*>(smem) + w*2560;
    unsigned short* vTw   = reinterpret_cast<unsigned short*>(smem + 20480) + w*1280;
    bf16x8 wb[2];
    #pragma unroll
    for (int et = 0; et < 2; ++et) {
        float4 wa = *reinterpret_cast<const float4*>(&W[(c + et*16)*32 + g*8]);
        float4 wb2 = *reinterpret_cast<const float4*>(&W[(c + et*16)*32 + g*8 + 4]);
        wb[et] = cvt8(wa, wb2);
    }
    float bias0 = bvec[c], bias1 = bvec[c + 16];
    f32x4 acc[4][2];
    #pragma unroll
    for (int i = 0; i < 4; ++i) { acc[i][0] = (f32x4){0.f,0.f,0.f,0.f}; acc[i][1] = (f32x4){0.f,0.f,0.f,0.f}; }
    f32x4 km0 = {0.f,0.f,0.f,0.f}, km1 = km0, km2 = km0, km3 = km0;

    for (int rnd = 0; rnd < 4; ++rnd) {
        int p0 = chunk*512 + w*128 + rnd*32;
        {
            uint4 vr0, vr1;
            size_t vbase = ((size_t)(b*NN + p0 + c*2))*128 + h*32 + g*8;
            vr0 = *reinterpret_cast<const uint4*>(&vb[vbase]);
            vr1 = *reinterpret_cast<const uint4*>(&vb[vbase + 128]);
            #pragma unroll
            for (int j = 0; j < 8; ++j) {
                ushort2 pk;
                pk.x = ((const unsigned short*)&vr0)[j];
                pk.y = ((const unsigned short*)&vr1)[j];
                *reinterpret_cast<ushort2*>(&vTw[(g*8 + j)*40 + c*2]) = pk;
            }
        }
        #pragma unroll
        for (int mt = 0; mt < 2; ++mt) {
            int posA = p0 + mt*16 + c;
            bf16x8 af = *reinterpret_cast<const bf16x8*>(&kb[((size_t)(b*NN + posA))*128 + h*32 + g*8]);
            f32x4 z4 = {0.f,0.f,0.f,0.f};
            f32x4 y0 = __builtin_amdgcn_mfma_f32_16x16x32_bf16(af, wb[0], z4, 0, 0, 0);
            f32x4 y1 = __builtin_amdgcn_mfma_f32_16x16x32_bf16(af, wb[1], z4, 0, 0, 0);
            f32x4 el0, eh0, el1, eh1;
            #pragma unroll
            for (int r = 0; r < 4; ++r) {
                float a0 = 2.f*(y0[r] + bias0);
                float a1 = 2.f*(y1[r] + bias1);
                el0[r] = __expf(a0); eh0[r] = __expf(-a0);
                el1[r] = __expf(a1); eh1[r] = __expf(-a1);
            }
            f32x4 s = el0 + eh0 + el1 + eh1;
            red16(s);
            f32x4 rs;
            #pragma unroll
            for (int r = 0; r < 4; ++r) rs[r] = rcpf(s[r]);
            f32x4 klo0 = el0*rs, khi0 = eh0*rs, klo1 = el1*rs, khi1 = eh1*rs;
            km0 += klo0; km1 += khi0; km2 += klo1; km3 += khi1;
            int posC = p0 + mt*16 + g*4;
            ushort4 wlo0, whi0, wlo1, whi1;
            #pragma unroll
            for (int r = 0; r < 4; ++r) {
                unsigned int u = fsc[((size_t)h*NN + posC + r)*16 + c];
                float fsv = bf2f((unsigned short)(u & 0xffffu));
                float fcv = bf2f((unsigned short)(u >> 16));
                ((unsigned short*)&wlo0)[r] = f2bf(klo0[r]*fcv + khi0[r]*fsv);
                ((unsigned short*)&whi0)[r] = f2bf(khi0[r]*fcv - klo0[r]*fsv);
                ((unsigned short*)&wlo1)[r] = f2bf(klo1[r] + khi1[r]);
                ((unsigned short*)&whi1)[r] = f2bf(khi1[r] - klo1[r]);
            }
            int po = mt*16 + g*4;
            *reinterpret_cast<ushort4*>(&kfsTw[(c)*40 + po])      = wlo0;
            *reinterpret_cast<ushort4*>(&kfsTw[(32 + c)*40 + po]) = whi0;
            *reinterpret_cast<ushort4*>(&kfsTw[(16 + c)*40 + po]) = wlo1;
            *reinterpret_cast<ushort4*>(&kfsTw[(48 + c)*40 + po]) = whi1;
        }
        {
            bf16x8 bf0 = *reinterpret_cast<const bf16x8*>(&vTw[(c)*40 + g*8]);
            bf16x8 bf1 = *reinterpret_cast<const bf16x8*>(&vTw[(16 + c)*40 + g*8]);
            #pragma unroll
            for (int mt = 0; mt < 4; ++mt) {
                bf16x8 af2 = *reinterpret_cast<const bf16x8*>(&kfsTw[(mt*16 + c)*40 + g*8]);
                acc[mt][0] = __builtin_amdgcn_mfma_f32_16x16x32_bf16(af2, bf0, acc[mt][0], 0, 0, 0);
                acc[mt][1] = __builtin_amdgcn_mfma_f32_16x16x32_bf16(af2, bf1, acc[mt][1], 0, 0, 0);
            }
        }
    }
    float kv0 = km0[0]+km0[1]+km0[2]+km0[3];
    float kv1 = km1[0]+km1[1]+km1[2]+km1[3];
    float kv2 = km2[0]+km2[1]+km2[2]+km2[3];
    float kv3 = km3[0]+km3[1]+km3[2]+km3[3];
    kv0 += __shfl_xor(kv0, 16); kv0 += __shfl_xor(kv0, 32);
    kv1 += __shfl_xor(kv1, 16); kv1 += __shfl_xor(kv1, 32);
    kv2 += __shfl_xor(kv2, 16); kv2 += __shfl_xor(kv2, 32);
    kv3 += __shfl_xor(kv3, 16); kv3 += __shfl_xor(kv3, 32);
    if (g == 0) {
        kms[w][c] = kv0; kms[w][16 + c] = kv2; kms[w][32 + c] = kv1; kms[w][48 + c] = kv3;
    }
    __syncthreads();
    float* kvred = reinterpret_cast<float*>(smem);
    #pragma unroll
    for (int mt = 0; mt < 4; ++mt)
        #pragma unroll
        for (int nt = 0; nt < 2; ++nt) {
            int d = nt*16 + c;
            *reinterpret_cast<f32x4*>(&kvred[(size_t)(w*32 + d)*68 + mt*16 + g*4]) = acc[mt][nt];
        }
    __syncthreads();
    #pragma unroll
    for (int i = 0; i < 8; ++i) {
        int idx = t*8 + i;
        int f = idx >> 5, d = idx & 31;
        float s2 = kvred[(0*32 + d)*68 + f] + kvred[(1*32 + d)*68 + f]
                 + kvred[(2*32 + d)*68 + f] + kvred[(3*32 + d)*68 + f];
        kvpart[((size_t)(bh*32 + chunk))*2048 + idx] = s2;
    }
    if (t < 64) {
        float s2 = kms[0][t] + kms[1][t] + kms[2][t] + kms[3][t];
        kmpart[(size_t)(bh*32 + chunk)*64 + t] = s2;
    }
}

// ---------------------------------------------------------------- reduce kv partials -> kvT bf16 [bh][d][f]; + kmean
__global__ __launch_bounds__(256) void k_kvred2(const float* __restrict__ kvpart, const float* __restrict__ kmpart,
                                                unsigned short* __restrict__ kvT, float* __restrict__ kmean)
{
    int bh = blockIdx.x >> 3, part = blockIdx.x & 7;
    int idx = part*256 + threadIdx.x;
    float s = 0.f;
    for (int cidx = 0; cidx < 32; ++cidx) s += kvpart[((size_t)(bh*32 + cidx))*2048 + idx];
    int f = idx >> 5, d = idx & 31;
    kvT[(size_t)bh*2048 + d*64 + f] = f2bf(s * (1.f/16384.f));
    if (part == 0 && threadIdx.x < 64) {
        int tt = threadIdx.x;
        float sm = 0.f;
        for (int cidx = 0; cidx < 32; ++cidx) sm += kmpart[(size_t)(bh*32 + cidx)*64 + tt];
        kmean[bh*64 + tt] = sm * (1.f/16384.f);
    }
}

// ---------------------------------------------------------------- fused q-features (MFMA) + xs (MFMA) -> xsb bf16
// grid (64 chunks, 32 bh); wave owns 64 pos as 2 rounds x 32. 8 blocks/CU.
__global__ __launch_bounds__(256) void k_featxs(
    const unsigned short* __restrict__ qb, const float* __restrict__ W, const float* __restrict__ bvec,
    const unsigned int* __restrict__ fsc, const unsigned short* __restrict__ kvT,
    const float* __restrict__ kmean, const unsigned short* __restrict__ xspb, unsigned short* __restrict__ xsb)
{
    __shared__ __align__(16) unsigned short qfs[4][32][72];
    int bh = blockIdx.y, b = bh >> 2, h = bh & 3;
    int chunk = blockIdx.x;
    int t = threadIdx.x, w = t >> 6, lane = t & 63;
    int c = lane & 15, g = lane >> 4;
    bf16x8 wb[2];
    #pragma unroll
    for (int et = 0; et < 2; ++et) {
        float4 wa = *reinterpret_cast<const float4*>(&W[(c + et*16)*32 + g*8]);
        float4 wb2 = *reinterpret_cast<const float4*>(&W[(c + et*16)*32 + g*8 + 4]);
        wb[et] = cvt8(wa, wb2);
    }
    float bias0 = bvec[c], bias1 = bvec[c + 16];
    float kml0 = kmean[bh*64 + c],      kml1 = kmean[bh*64 + 16 + c];
    float kmh0 = kmean[bh*64 + 32 + c], kmh1 = kmean[bh*64 + 48 + c];
    bf16x8 bkv[2][2];
    #pragma unroll
    for (int nt = 0; nt < 2; ++nt)
        #pragma unroll
        for (int ks = 0; ks < 2; ++ks)
            bkv[nt][ks] = *reinterpret_cast<const bf16x8*>(&kvT[(size_t)bh*2048 + (nt*16 + c)*64 + ks*32 + g*8]);

    for (int rnd = 0; rnd < 2; ++rnd) {
        int p0 = chunk*256 + w*64 + rnd*32;
        #pragma unroll
        for (int mt = 0; mt < 2; ++mt) {
            int posA = p0 + mt*16 + c;
            bf16x8 af = *reinterpret_cast<const bf16x8*>(&qb[((size_t)(b*NN + posA))*128 + h*32 + g*8]);
            f32x4 z4 = {0.f,0.f,0.f,0.f};
            f32x4 y0 = __builtin_amdgcn_mfma_f32_16x16x32_bf16(af, wb[0], z4, 0, 0, 0);
            f32x4 y1 = __builtin_amdgcn_mfma_f32_16x16x32_bf16(af, wb[1], z4, 0, 0, 0);
            f32x4 el0, eh0, el1, eh1;
            #pragma unroll
            for (int r = 0; r < 4; ++r) {
                float a0 = 2.f*(y0[r] + bias0);
                float a1 = 2.f*(y1[r] + bias1);
                el0[r] = __expf(a0); eh0[r] = __expf(-a0);
                el1[r] = __expf(a1); eh1[r] = __expf(-a1);
            }
            f32x4 s = el0 + eh0 + el1 + eh1;
            f32x4 wv = el0*kml0 + eh0*kmh0 + el1*kml1 + eh1*kmh1;
            red16x2(s, wv);
            f32x4 zr;
            #pragma unroll
            for (int r = 0; r < 4; ++r) {
                float rs = rcpf(s[r]);
                float z = rcpf(wv[r]*rs + 1e-6f);
                zr[r] = z*rs;
            }
            int posC = mt*16 + g*4;
            #pragma unroll
            for (int r = 0; r < 4; ++r) {
                unsigned int u = fsc[((size_t)h*NN + p0 + posC + r)*16 + c];
                float fsv = bf2f((unsigned short)(u & 0xffffu));
                float fcv = bf2f((unsigned short)(u >> 16));
                qfs[w][posC + r][c]      = f2bf(zr[r]*(el0[r]*fcv + eh0[r]*fsv));
                qfs[w][posC + r][32 + c] = f2bf(zr[r]*(eh0[r]*fcv - el0[r]*fsv));
                qfs[w][posC + r][16 + c] = f2bf(zr[r]*(el1[r] + eh1[r]));
                qfs[w][posC + r][48 + c] = f2bf(zr[r]*(eh1[r] - el1[r]));
            }
        }
        f32x4 acc[2][2];
        #pragma unroll
        for (int i = 0; i < 2; ++i) { acc[i][0] = (f32x4){0.f,0.f,0.f,0.f}; acc[i][1] = (f32x4){0.f,0.f,0.f,0.f}; }
        #pragma unroll
        for (int ks = 0; ks < 2; ++ks)
            #pragma unroll
            for (int mt = 0; mt < 2; ++mt) {
                bf16x8 af2 = *reinterpret_cast<const bf16x8*>(&qfs[w][mt*16 + c][ks*32 + g*8]);
                acc[mt][0] = __builtin_amdgcn_mfma_f32_16x16x32_bf16(af2, bkv[0][ks], acc[mt][0], 0, 0, 0);
                acc[mt][1] = __builtin_amdgcn_mfma_f32_16x16x32_bf16(af2, bkv[1][ks], acc[mt][1], 0, 0, 0);
            }
        #pragma unroll
        for (int mt = 0; mt < 2; ++mt)
            #pragma unroll
            for (int nt = 0; nt < 2; ++nt) {
                int d = nt*16 + c;
                #pragma unroll
                for (int r = 0; r < 4; ++r) {
                    int pos = p0 + mt*16 + g*4 + r;
                    size_t off = ((size_t)(b*NN + pos))*128 + h*32 + d;
                    xsb[off] = f2bf(bf2f(xspb[off]) + acc[mt][nt][r]);
                }
            }
    }
}

// ---------------------------------------------------------------- gram via MFMA + fused norms; atomics into L2-resident G
// grid (32 kc, 8 b); per block K=512
__global__ __launch_bounds__(256) void k_gram(const unsigned short* __restrict__ qb, const unsigned short* __restrict__ kb,
                                              float* __restrict__ G,
                                              float* __restrict__ qn2, float* __restrict__ kn2)
{
    __shared__ unsigned short qTs[128][40];
    __shared__ unsigned short kTs[128][40];
    int kc = blockIdx.x, bb = blockIdx.y;
    int t = threadIdx.x, lane = t & 63;
    int wave = t >> 6, wm = wave >> 1, wn = wave & 1;
    int c = t & 127, lh = t >> 7;
    float qa = 0.f, ka = 0.f;
    f32x4 acc[4][4];
    #pragma unroll
    for (int i = 0; i < 4; ++i)
        #pragma unroll
        for (int j = 0; j < 4; ++j) acc[i][j] = (f32x4){0.f,0.f,0.f,0.f};

    for (int kt = 0; kt < 16; ++kt) {
        __syncthreads();
        #pragma unroll
        for (int i = 0; i < 16; ++i) {
            int l = lh*16 + i;
            size_t pos = (size_t)bb*NN + kc*512 + kt*32 + l;
            unsigned short qu = qb[pos*128 + c];
            unsigned short ku = kb[pos*128 + c];
            float qv = bf2f(qu), kvv = bf2f(ku);
            qa += qv*qv; ka += kvv*kvv;
            qTs[c][l] = qu;
            kTs[c][l] = ku;
        }
        __syncthreads();
        bf16x8 af[4];
        #pragma unroll
        for (int mi = 0; mi < 4; ++mi)
            af[mi] = *reinterpret_cast<const bf16x8*>(&qTs[wm*64 + mi*16 + (lane & 15)][(lane >> 4)*8]);
        #pragma unroll
        for (int ni = 0; ni < 4; ++ni) {
            bf16x8 bfr = *reinterpret_cast<const bf16x8*>(&kTs[wn*64 + ni*16 + (lane & 15)][(lane >> 4)*8]);
            #pragma unroll
            for (int mi = 0; mi < 4; ++mi)
                acc[mi][ni] = __builtin_amdgcn_mfma_f32_16x16x32_bf16(af[mi], bfr, acc[mi][ni], 0, 0, 0);
        }
    }
    #pragma unroll
    for (int mi = 0; mi < 4; ++mi) {
        #pragma unroll
        for (int ni = 0; ni < 4; ++ni) {
            int d = wn*64 + ni*16 + (lane & 15);
            #pragma unroll
            for (int r = 0; r < 4; ++r) {
                int cc = wm*64 + mi*16 + (lane >> 4)*4 + r;
                atomicAdd(&G[(size_t)bb*16384 + (size_t)cc*128 + d], acc[mi][ni][r]);
            }
        }
    }
    atomicAdd(&qn2[bb*128 + c], qa);
    atomicAdd(&kn2[bb*128 + c], ka);
}

// ---------------------------------------------------------------- channel attention softmax
__global__ __launch_bounds__(128) void k_attnsm(const float* __restrict__ G, const float* __restrict__ qn2,
    const float* __restrict__ kn2, const float* __restrict__ temp, float* __restrict__ attn)
{
    __shared__ float red[128];
    int row = blockIdx.x;
    int b = row >> 7, c = row & 127;
    int t = threadIdx.x;
    float s0 = G[(size_t)b*16384 + (size_t)c*128 + t];
    float qn = fmaxf(sqrtf(qn2[b*128 + c]), 1e-12f);
    float kn = fmaxf(sqrtf(kn2[b*128 + t]), 1e-12f);
    float val = s0 / (qn*kn) * temp[c];
    red[t] = val; __syncthreads();
    for (int s = 64; s > 0; s >>= 1) { if (t < s) red[t] = fmaxf(red[t], red[t+s]); __syncthreads(); }
    float mm = red[0]; __syncthreads();
    float ev = expf(val - mm);
    red[t] = ev; __syncthreads();
    for (int s = 64; s > 0; s >>= 1) { if (t < s) red[t] += red[t+s]; __syncthreads(); }
    attn[(size_t)row*128 + t] = ev / red[0];
}

// ---------------------------------------------------------------- per-batch B matrix, transposed bf16
__global__ __launch_bounds__(256) void k_bmat(const float* __restrict__ attn, const float* __restrict__ Wp,
                                              unsigned short* __restrict__ BmatT)
{
    int b = blockIdx.y, kk = blockIdx.x, o = threadIdx.x;
    float val;
    if (kk < 128) {
        val = Wp[(size_t)o*256 + kk];
    } else {
        int d = kk - 128;
        __shared__ float a[128];
        if (o < 128) a[o] = attn[((size_t)b*128 + o)*128 + d];
        __syncthreads();
        float acc = 0.f;
        for (int c = 0; c < 128; ++c) acc += a[c] * Wp[(size_t)o*256 + 128 + c];
        val = acc;
    }
    BmatT[((size_t)b*256 + o)*256 + kk] = f2bf(val);
}

// ---------------------------------------------------------------- final MFMA GEMM with T14 prefetch (direct-store epilogue)
__global__ __launch_bounds__(256) void k_out_mfma(const unsigned short* __restrict__ xsb,
    const unsigned short* __restrict__ vb, const unsigned short* __restrict__ BmatT,
    const float* __restrict__ bp, float* __restrict__ out)
{
    __shared__ unsigned short Asm[128*64];
    __shared__ unsigned short Bsm[128*64];
    int t = threadIdx.x;
    int lin = blockIdx.y*2 + blockIdx.x;
    int logical = (lin & 7)*256 + (lin >> 3);
    int ntile = logical & 1;
    int mtile = logical >> 1;
    int m0 = mtile * 128;
    int n0 = ntile * 128;
    int b = mtile >> 7;
    int wave = t >> 6, lane = t & 63;
    int wm = wave >> 1, wn = wave & 1;
    int lrow = lane & 15, lk = lane >> 4;
    f32x4 acc[4][4];
    #pragma unroll
    for (int i = 0; i < 4; ++i)
        #pragma unroll
        for (int j = 0; j < 4; ++j) acc[i][j] = (f32x4){0.f,0.f,0.f,0.f};

    int am = t >> 3, ak8 = t & 7;
    uint4 pa4[4];
    #pragma unroll
    for (int p = 0; p < 4; ++p)
        pa4[p] = *reinterpret_cast<const uint4*>(&xsb[(size_t)(m0 + am + p*32)*128 + ak8*8]);

    #pragma unroll
    for (int kt = 0; kt < 4; ++kt) {
        if (kt) __syncthreads();
        #pragma unroll
        for (int p = 0; p < 4; ++p) {
            int m = am + p*32;
            int byte = m*128 + ((ak8 ^ (m & 7)) << 4);
            *reinterpret_cast<uint4*>(reinterpret_cast<char*>(Asm) + byte) = pa4[p];
        }
        {
            int n = t >> 3, k8 = t & 7;
            #pragma unroll
            for (int p = 0; p < 4; ++p, n += 32) {
                uint4 u4 = *reinterpret_cast<const uint4*>(&BmatT[((size_t)b*256 + n0 + n)*256 + kt*64 + k8*8]);
                int byte = n*128 + ((k8 ^ (n & 7)) << 4);
                *reinterpret_cast<uint4*>(reinterpret_cast<char*>(Bsm) + byte) = u4;
            }
        }
        if (kt < 3) {
            const unsigned short* Asrc = ((kt+1) < 2) ? xsb : vb;
            int ka0 = ((kt+1) & 1) * 64;
            #pragma unroll
            for (int p = 0; p < 4; ++p)
                pa4[p] = *reinterpret_cast<const uint4*>(&Asrc[(size_t)(m0 + am + p*32)*128 + ka0 + ak8*8]);
        }
        __syncthreads();
        #pragma unroll
        for (int ks = 0; ks < 2; ++ks) {
            bf16x8 af[4], bfv[4];
            #pragma unroll
            for (int mi = 0; mi < 4; ++mi) {
                int m = wm*64 + mi*16 + lrow;
                int u = (ks*4 + lk) ^ (m & 7);
                af[mi] = *reinterpret_cast<const bf16x8*>(reinterpret_cast<const char*>(Asm) + m*128 + u*16);
            }
            #pragma unroll
            for (int ni = 0; ni < 4; ++ni) {
                int n = wn*64 + ni*16 + lrow;
                int u = (ks*4 + lk) ^ (n & 7);
                bfv[ni] = *reinterpret_cast<const bf16x8*>(reinterpret_cast<const char*>(Bsm) + n*128 + u*16);
            }
            #pragma unroll
            for (int mi = 0; mi < 4; ++mi)
                #pragma unroll
                for (int ni = 0; ni < 4; ++ni)
                    acc[mi][ni] = __builtin_amdgcn_mfma_f32_16x16x32_bf16(af[mi], bfv[ni], acc[mi][ni], 0, 0, 0);
        }
    }
    #pragma unroll
    for (int mi = 0; mi < 4; ++mi) {
        #pragma unroll
        for (int ni = 0; ni < 4; ++ni) {
            int gcol = n0 + wn*64 + ni*16 + lrow;
            float bias = bp[gcol];
            #pragma unroll
            for (int r = 0; r < 4; ++r) {
                size_t grow = (size_t)m0 + wm*64 + mi*16 + lk*4 + r;
                __builtin_nontemporal_store(acc[mi][ni][r] + bias, &out[grow*256 + gcol]);
            }
        }
    }
}

extern "C" void kernel_launch(void* const* d_in, const int* in_sizes, int n_in,
                              void* d_out, int out_size, void* d_ws, size_t ws_size,
                              hipStream_t stream)
{
    (void)in_sizes; (void)n_in; (void)out_size; (void)ws_size;
    const float* x    = (const float*)d_in[0];
    const float* Wq   = (const float*)d_in[1];
    const float* bq   = (const float*)d_in[2];
    const float* Wk   = (const float*)d_in[3];
    const float* bk   = (const float*)d_in[4];
    const float* Wv   = (const float*)d_in[5];
    const float* bv   = (const float*)d_in[6];
    const float* Whq  = (const float*)d_in[7];
    const float* bhq  = (const float*)d_in[8];
    const float* Whk  = (const float*)d_in[9];
    const float* bhk  = (const float*)d_in[10];
    const float* sinc = (const float*)d_in[11];
    const float* cosc = (const float*)d_in[12];
    const float* lw   = (const float*)d_in[13];
    const float* lb   = (const float*)d_in[14];
    const float* temp = (const float*)d_in[15];
    const float* Wp   = (const float*)d_in[16];
    const float* bp   = (const float*)d_in[17];

    float* out = (float*)d_out;
    float* q   = out + 33554432;
    float* k   = out + 50331648;
    float* ws  = (float*)d_ws;

    unsigned short* xspb = (unsigned short*)(ws + WS_XSPB);
    float* G      = ws + WS_G;
    unsigned short* vbuf = (unsigned short*)(ws + WS_VB);
    unsigned short* xsb  = (unsigned short*)(ws + WS_XSB);
    unsigned int* fsc = (unsigned int*)(ws + WS_FS);
    float* inv    = ws + WS_INV;
    float* cs     = ws + WS_CS;
    float* cc     = ws + WS_CC;
    unsigned short* Wc = (unsigned short*)(ws + WS_WCAT);
    float* bcat   = ws + WS_BCAT;
    float* kvpart = ws + WS_KVPART;
    float* kmpart = ws + WS_KMPART;
    unsigned short* kvT = (unsigned short*)(ws + WS_KV);
    float* kmean  = ws + WS_KMEAN;
    float* qn2    = ws + WS_QN2;
    float* kn2    = ws + WS_KN2;
    float* attn   = ws + WS_ATTN;
    unsigned short* BmatT = (unsigned short*)(ws + WS_BMATT);
    unsigned short* qbuf  = (unsigned short*)(ws + WS_QB);
    unsigned short* kbuf  = (unsigned short*)(ws + WS_KB);

    hipMemsetAsync(qn2, 0, 2048*sizeof(float), stream);
    hipMemsetAsync(G, 0, 131072*sizeof(float), stream);

    k_wprep<<<385, 256, 0, stream>>>(Wq, Wk, Wv, bq, bk, bv, sinc, cosc, Wc, bcat, inv, cs, cc);
    k_tables<<<4096, 256, 0, stream>>>(inv, cs, cc, fsc);
    k_qkv_mfma<<<1024, 512, 0, stream>>>(x, Wc, bcat, q, k, qbuf, kbuf, vbuf);
    k_conv<<<dim3(8, 128, 8), 256, 0, stream>>>(vbuf, lw, lb, xspb);
    k_featkv<<<dim3(32, 32), 256, 0, stream>>>(kbuf, vbuf, Whk, bhk, fsc, kvpart, kmpart);
    k_kvred2<<<256, 256, 0, stream>>>(kvpart, kmpart, kvT, kmean);
    k_featxs<<<dim3(64, 32), 256, 0, stream>>>(qbuf, Whq, bhq, fsc, kvT, kmean, xspb, xsb);
    k_gram<<<dim3(32, 8), 256, 0, stream>>>(qbuf, kbuf, G, qn2, kn2);
    k_attnsm<<<1024, 128, 0, stream>>>(G, qn2, kn2, temp, attn);
    k_bmat<<<dim3(256, 8), 256, 0, stream>>>(attn, Wp, BmatT);
    k_out_mfma<<<dim3(2, 1024), 256, 0, stream>>>(xsb, vbuf, BmatT, bp, out);
}